// Round 13
// baseline (177.772 us; speedup 1.0000x reference)
//
#include <hip/hip_runtime.h>
#include <hip/hip_bf16.h>
#include <cstdint>

typedef __bf16 bf16x8 __attribute__((ext_vector_type(8)));
typedef float f32x4 __attribute__((ext_vector_type(4)));
typedef float f32x16 __attribute__((ext_vector_type(16)));
typedef unsigned int u32;
typedef unsigned short u16;
typedef u32 u32x4 __attribute__((ext_vector_type(4)));

#define AS1 __attribute__((address_space(1)))
#define AS3 __attribute__((address_space(3)))

static __device__ __forceinline__ void gld16(const void* g, void* l) {
  __builtin_amdgcn_global_load_lds((const AS1 u32*)g, (AS3 u32*)l, 16, 0, 0);
}
static __device__ __forceinline__ u16 f2b(float f) {
  return __builtin_bit_cast(u16, __float2bfloat16(f));
}
static __device__ __forceinline__ float b2f(u16 u) {
  return __bfloat162float(__builtin_bit_cast(__hip_bfloat16, u));
}
// one-instruction pack: lo = bf16(a), hi = bf16(b)
static __device__ __forceinline__ u32 cvtpk(float a, float b) {
  u32 r;
  asm("v_cvt_pk_bf16_f32 %0, %1, %2" : "=v"(r) : "v"(a), "v"(b));
  return r;
}

// ---------------- RoPE tables: cos/sin[t][i], t<2048, i<64 ----------------
__global__ void k_tables(float* __restrict__ cost, float* __restrict__ sint) {
  const int idx = blockIdx.x * 256 + threadIdx.x;   // 131072 total
  const int t = idx >> 6, i = idx & 63;
  const float inv = exp2f(-(float)(2 * i) * (13.287712379549449f / 128.0f));
  const float f = (float)t * inv;
  cost[idx] = cosf(f);
  sint[idx] = sinf(f);
}

// ---------------- fp32 -> bf16 convert of x, Wq, Wk, Wv ----------------
__global__ void k_convert(const float* __restrict__ x, const float* __restrict__ wq,
                          const float* __restrict__ wk, const float* __restrict__ wv,
                          u16* __restrict__ xb, u16* __restrict__ wqb,
                          u16* __restrict__ wkb, u16* __restrict__ wvb) {
  for (int i4 = blockIdx.x * blockDim.x + threadIdx.x; i4 < 3670016;
       i4 += gridDim.x * blockDim.x) {
    const int e = i4 * 4;
    const float* s; u16* d;
    if (e < 8388608)        { s = x  + e;              d = xb  + e; }
    else if (e < 12582912)  { int o = e - 8388608;  s = wq + o; d = wqb + o; }
    else if (e < 13631488)  { int o = e - 12582912; s = wk + o; d = wkb + o; }
    else                    { int o = e - 13631488; s = wv + o; d = wvb + o; }
    const float4 v = *(const float4*)s;
    ushort4 o4;
    o4.x = f2b(v.x); o4.y = f2b(v.y); o4.z = f2b(v.z); o4.w = f2b(v.w);
    *(ushort4*)d = o4;
  }
}

// ---------------- fused QKV projection GEMM (bf16 MFMA, m97 structure) ----------------
// vT is written with token-index bits 2<->3 swapped (within each 16-token group):
// makes attention's PV B-fragment equal the lane's OWN softmax values (no shfl).
__global__ __launch_bounds__(256) void k_gemm(
    const u16* __restrict__ xb, const u16* __restrict__ wqb,
    const u16* __restrict__ wkb, const u16* __restrict__ wvb,
    u16* __restrict__ qb, u16* __restrict__ kb, u16* __restrict__ vT) {
  __shared__ __align__(16) char smA[8192];   // [128][32] bf16, source-chunk-swizzled
  __shared__ __align__(16) char smB[8192];
  const int tid = threadIdx.x;
  const int w = tid >> 6, l = tid & 63;
  const int lm = l & 15, g = l >> 4;
  const int m0 = blockIdx.x << 7;
  const int j = blockIdx.y;
  const u16* W; u16* dst; int n0, ldc, vmode;
  if (j < 16)      { W = wqb; dst = qb; n0 = j << 7;        ldc = 2048; vmode = 0; }
  else if (j < 20) { W = wkb; dst = kb; n0 = (j - 16) << 7; ldc = 512;  vmode = 0; }
  else             { W = wvb; dst = vT; n0 = (j - 20) << 7; ldc = 0;    vmode = 1; }

  const int srow = w * 16 + (l >> 2);
  const int scol = l & 3;

  f32x4 acc[4][4];
  #pragma unroll
  for (int a = 0; a < 4; ++a)
    #pragma unroll
    for (int bb = 0; bb < 4; ++bb) { f32x4 zz = {0.f, 0.f, 0.f, 0.f}; acc[a][bb] = zz; }

  const int wm = (w >> 1) << 6, wn = (w & 1) << 6;

  for (int k0 = 0; k0 < 2048; k0 += 32) {
    #pragma unroll
    for (int i = 0; i < 2; ++i) {
      const int r = srow + (i << 6);
      const int sc = (scol ^ (r & 3)) << 3;
      gld16(xb + (m0 + r) * 2048 + k0 + sc, smA + ((i * 4 + w) << 10));
      gld16(W  + (n0 + r) * 2048 + k0 + sc, smB + ((i * 4 + w) << 10));
    }
    __syncthreads();
    bf16x8 af[4], bfr[4];
    #pragma unroll
    for (int mt = 0; mt < 4; ++mt) {
      const int row = wm + mt * 16 + lm;
      af[mt] = *(const bf16x8*)(smA + row * 64 + ((g ^ (row & 3)) << 4));
    }
    #pragma unroll
    for (int nt = 0; nt < 4; ++nt) {
      const int row = wn + nt * 16 + lm;
      bfr[nt] = *(const bf16x8*)(smB + row * 64 + ((g ^ (row & 3)) << 4));
    }
    #pragma unroll
    for (int mt = 0; mt < 4; ++mt)
      #pragma unroll
      for (int nt = 0; nt < 4; ++nt)
        acc[mt][nt] = __builtin_amdgcn_mfma_f32_16x16x32_bf16(af[mt], bfr[nt], acc[mt][nt], 0, 0, 0);
    __syncthreads();
  }

  const int gs = ((g & 1) << 1) | (g >> 1);   // token-index bit2<->bit3 swap for vT
  #pragma unroll
  for (int mt = 0; mt < 4; ++mt) {
    #pragma unroll
    for (int nt = 0; nt < 4; ++nt) {
      const int n = n0 + wn + nt * 16 + lm;
      #pragma unroll
      for (int r = 0; r < 4; ++r) {
        const u16 hv = f2b(acc[mt][nt][r]);
        if (!vmode) {
          const int mq = m0 + wm + mt * 16 + g * 4 + r;
          dst[mq * ldc + n] = hv;
        } else {
          const int mv = m0 + wm + mt * 16 + gs * 4 + r;
          dst[n * 4096 + mv] = hv;
        }
      }
    }
  }
}

// ---------------- RMSNorm + RoPE in-place on q and k ----------------
// q additionally pre-scaled by log2(e)/sqrt(128) so attention skips the scale.
// Consequence: attention scores s in [-16.4, 16.4] -> no online max needed.
__global__ __launch_bounds__(256) void k_normrope(u16* __restrict__ qb, u16* __restrict__ kb,
                                                  const float* __restrict__ cost,
                                                  const float* __restrict__ sint) {
  const int item = blockIdx.x * 4 + (threadIdx.x >> 6);
  const int l = threadIdx.x & 63;
  u16* p; int tpos; float qs;
  if (item < 65536) { p = qb + item * 128; tpos = (item >> 4) & 2047; qs = 0.12751742f; }
  else { const int ik = item - 65536; p = kb + ik * 128; tpos = (ik >> 2) & 2047; qs = 1.0f; }
  const float f1 = b2f(p[l]);
  const float f2 = b2f(p[l + 64]);
  float ss = f1 * f1 + f2 * f2;
  #pragma unroll
  for (int d = 1; d < 64; d <<= 1) ss += __shfl_xor(ss, d);
  const float rn = rsqrtf(ss * (1.0f / 128.0f) + 1.1920928955078125e-07f);
  const float c = cost[tpos * 64 + l], s = sint[tpos * 64 + l];
  const float x1 = f1 * rn, x2 = f2 * rn;
  p[l]      = f2b((x1 * c + x2 * s) * qs);
  p[l + 64] = f2b((x2 * c - x1 * s) * qs);
}

// ---------------- causal GQA flash attention: no-max softmax, cross-block kv-split ---
// grid (1536): bid&7 = (b,hkv) XCD-local; hsub = (bid>>3)&3; u = bid>>5 in [0,48).
// u<32: SPLIT block for tile tau = 31-(u>>1), parity hsp = u&1 — handles kv64-chunks
//   {hsp, hsp+2, ...} <= tau (disjoint interleave, R = 8..16 rounds). half0 writes
//   unnormalized O into out + ll0; half1 writes O1 (ws) + ll1; k_merge combines.
// u>=32: SHORT block tau = 47-u (R = tau+1 <= 16), direct normalized write.
// Critical path capped at 16 rounds. Inner round math identical to round-11.
__global__ __launch_bounds__(128) void k_attn(
    const u16* __restrict__ qb, const u16* __restrict__ kb,
    const u16* __restrict__ vT, float* __restrict__ out,
    float* __restrict__ out1, float* __restrict__ ll0t, float* __restrict__ ll1t) {
  __shared__ __align__(16) char lds[32768];   // [stream][K 8K | V 8K]
  const int tid = threadIdx.x;
  const int l = tid & 63;
  const int w = tid >> 6;          // wave 0/1 -> q offset 32*w
  const int lq = l & 31;
  const int hi = l >> 5;

  const int bid = blockIdx.x;
  const int cxc = bid & 7;
  const int bb  = cxc >> 2, hkv = cxc & 3;
  const int hsub = (bid >> 3) & 3;
  const int h   = hkv * 4 + hsub;
  const int u   = bid >> 5;              // 0..47
  const bool split = (u < 32);
  const int tau = split ? (31 - (u >> 1)) : (47 - u);
  const int hsp = split ? (u & 1) : 0;
  const int R   = split ? (((tau - hsp) >> 1) + 1) : (tau + 1);

  const u16* kbase = kb + ((size_t)bb * 2048) * 512 + hkv * 128;
  const u16* vbase = vT + ((size_t)(hkv * 128)) * 4096 + (size_t)bb * 2048;
  const u16* qhb   = qb + ((size_t)bb * 2048) * 2048 + h * 128;

  const int krow_t = tid >> 4, kch = tid & 15;   // K staging coords
  const int vrow_t = tid >> 2, vch = tid & 3;    // V staging coords

  const int qabs = tau * 64 + w * 32 + lq;
  const int qmin = tau * 64 + w * 32;

  bf16x8 qf[8];
  {
    const u16* qp = qhb + (size_t)qabs * 2048;
    #pragma unroll
    for (int c = 0; c < 8; ++c) qf[c] = *(const bf16x8*)(qp + c * 16 + hi * 8);
  }
  f32x16 oacc[4], sA, sB;
  #pragma unroll
  for (int dt = 0; dt < 4; ++dt)
    #pragma unroll
    for (int e = 0; e < 16; ++e) oacc[dt][e] = 0.f;
  float llA = 0.f, llB = 0.f;

  // stage one 32-kv tile (16 KB: K 8K + V 8K), 128 threads x 8 gld16
  auto STAGE = [&](int st, int jb2) {
    char* bK = lds + st * 16384;
    char* bV = bK + 8192;
    #pragma unroll
    for (int uu = 0; uu < 4; ++uu) {
      const int kr = uu * 8 + krow_t;
      gld16(kbase + (size_t)(jb2 + kr) * 512 + ((kch ^ (kr & 15)) << 3),
            bK + uu * 2048 + tid * 16);
      // V paired-row layout: slot (R0, C0) holds V[2*R0 + (cp>>2)][8*(cp&3) ..]
      const int R0 = uu * 16 + (vrow_t >> 1);         // 0..63
      const int C0 = ((vrow_t & 1) << 2) + vch;       // 0..7
      const int cp = C0 ^ (R0 & 7);
      const int vd = 2 * R0 + (cp >> 2);              // d row 0..127
      gld16(vbase + (size_t)vd * 4096 + jb2 + ((cp & 3) << 3),
            bV + uu * 2048 + tid * 16);
    }
  };

  const int c0 = hsp;                    // first chunk (short: hsp==0)
  STAGE(0, c0 * 64);
  STAGE(1, c0 * 64 + 32);
  __syncthreads();

  for (int r = 0; r < R; ++r) {
    const int c = split ? (hsp + 2 * r) : r;

    // ---- QK^T for both 32-kv halves of chunk c (independent MFMA chains) ----
    #pragma unroll
    for (int e = 0; e < 16; ++e) { sA[e] = 0.f; sB[e] = 0.f; }
    const char* skA = lds;
    const char* skB = lds + 16384;
    #pragma unroll
    for (int cc = 0; cc < 8; ++cc) {
      const int ch = ((2 * cc + hi) ^ (lq & 15)) << 4;
      const bf16x8 kfA = *(const bf16x8*)(skA + lq * 256 + ch);
      const bf16x8 kfB = *(const bf16x8*)(skB + lq * 256 + ch);
      sA = __builtin_amdgcn_mfma_f32_32x32x16_bf16(kfA, qf[cc], sA, 0, 0, 0);
      sB = __builtin_amdgcn_mfma_f32_32x32x16_bf16(kfB, qf[cc], sB, 0, 0, 0);
    }

    // ---- no-max softmax: p = exp2(s) (|s| <= 16.4 by RMS-norm bound) ----
    const int jbA = c * 64;
    const int jbB = c * 64 + 32;
    if (jbA + 31 > qmin) {
      #pragma unroll
      for (int e = 0; e < 16; ++e) {
        const int kvl = (e & 3) + ((e >> 2) << 3) + (hi << 2);
        if (jbA + kvl > qabs) sA[e] = -1e30f;
      }
    }
    if (jbB + 31 > qmin) {
      #pragma unroll
      for (int e = 0; e < 16; ++e) {
        const int kvl = (e & 3) + ((e >> 2) << 3) + (hi << 2);
        if (jbB + kvl > qabs) sB[e] = -1e30f;
      }
    }
    float rA = 0.f, rB = 0.f;
    #pragma unroll
    for (int e = 0; e < 16; e += 4) {
      const float a0 = exp2f(sA[e]),     a1 = exp2f(sA[e + 1]);
      const float a2 = exp2f(sA[e + 2]), a3 = exp2f(sA[e + 3]);
      const float b0 = exp2f(sB[e]),     b1 = exp2f(sB[e + 1]);
      const float b2 = exp2f(sB[e + 2]), b3 = exp2f(sB[e + 3]);
      sA[e] = a0; sA[e + 1] = a1; sA[e + 2] = a2; sA[e + 3] = a3;
      sB[e] = b0; sB[e + 1] = b1; sB[e + 2] = b2; sB[e + 3] = b3;
      rA += (a0 + a1) + (a2 + a3);
      rB += (b0 + b1) + (b2 + b3);
    }
    llA += rA; llB += rB;

    // ---- PV for both halves into shared oacc (additive merge) ----
    // Exchange-free: B-fragment = lane's own P values in order (vT pre-permuted).
    const char* svA = lds + 8192;
    const char* svB = lds + 16384 + 8192;
    #pragma unroll
    for (int cc = 0; cc < 2; ++cc) {
      const int c8 = cc * 8;
      u32x4 bwA, bwB;
      bwA.x = cvtpk(sA[c8 + 0], sA[c8 + 1]);
      bwA.y = cvtpk(sA[c8 + 2], sA[c8 + 3]);
      bwA.z = cvtpk(sA[c8 + 4], sA[c8 + 5]);
      bwA.w = cvtpk(sA[c8 + 6], sA[c8 + 7]);
      bwB.x = cvtpk(sB[c8 + 0], sB[c8 + 1]);
      bwB.y = cvtpk(sB[c8 + 2], sB[c8 + 3]);
      bwB.z = cvtpk(sB[c8 + 4], sB[c8 + 5]);
      bwB.w = cvtpk(sB[c8 + 6], sB[c8 + 7]);
      const bf16x8 pfA = __builtin_bit_cast(bf16x8, bwA);
      const bf16x8 pfB = __builtin_bit_cast(bf16x8, bwB);
      #pragma unroll
      for (int dt = 0; dt < 4; ++dt) {
        const int vrow = dt * 16 + (lq >> 1);
        const int cpre = ((lq & 1) << 2) + 2 * cc + hi;
        const int chv = (cpre ^ (vrow & 7)) << 4;
        const bf16x8 vfA = *(const bf16x8*)(svA + vrow * 128 + chv);
        oacc[dt] = __builtin_amdgcn_mfma_f32_32x32x16_bf16(vfA, pfA, oacc[dt], 0, 0, 0);
      }
      #pragma unroll
      for (int dt = 0; dt < 4; ++dt) {
        const int vrow = dt * 16 + (lq >> 1);
        const int cpre = ((lq & 1) << 2) + 2 * cc + hi;
        const int chv = (cpre ^ (vrow & 7)) << 4;
        const bf16x8 vfB = *(const bf16x8*)(svB + vrow * 128 + chv);
        oacc[dt] = __builtin_amdgcn_mfma_f32_32x32x16_bf16(vfB, pfB, oacc[dt], 0, 0, 0);
      }
    }

    // ---- restage (single buffer): wait for readers, stage, wait for data ----
    if (r + 1 < R) {
      const int c2 = split ? (c + 2) : (c + 1);
      __syncthreads();                 // all waves done reading this round
      STAGE(0, c2 * 64);
      STAGE(1, c2 * 64 + 32);
      __syncthreads();                 // vmcnt(0) drain + visibility
    }
  }

  // ---- epilogue ----
  float ll = llA + llB;
  ll += __shfl_xor(ll, 32);
  if (!split) {
    const float inv = 1.0f / ll;
    float* ob = out + ((size_t)(bb * 2048 + qabs)) * 2048 + h * 128;
    #pragma unroll
    for (int dt = 0; dt < 4; ++dt)
      #pragma unroll
      for (int qd = 0; qd < 4; ++qd) {
        float4 o4;
        o4.x = oacc[dt][qd * 4 + 0] * inv;
        o4.y = oacc[dt][qd * 4 + 1] * inv;
        o4.z = oacc[dt][qd * 4 + 2] * inv;
        o4.w = oacc[dt][qd * 4 + 3] * inv;
        *(float4*)(ob + dt * 32 + qd * 8 + hi * 4) = o4;
      }
  } else {
    const int rp = bb * 1024 + qabs - 1024;   // region row (qabs >= 1024 for tau>=16)
    float* ob = (hsp == 0)
        ? out  + ((size_t)(bb * 2048 + qabs)) * 2048 + h * 128
        : out1 + (size_t)rp * 2048 + h * 128;
    #pragma unroll
    for (int dt = 0; dt < 4; ++dt)
      #pragma unroll
      for (int qd = 0; qd < 4; ++qd) {
        float4 o4;
        o4.x = oacc[dt][qd * 4 + 0];
        o4.y = oacc[dt][qd * 4 + 1];
        o4.z = oacc[dt][qd * 4 + 2];
        o4.w = oacc[dt][qd * 4 + 3];
        *(float4*)(ob + dt * 32 + qd * 8 + hi * 4) = o4;
      }
    if (hi == 0) {
      float* llt = hsp ? ll1t : ll0t;
      llt[rp * 16 + h] = ll;
    }
  }
}

// ---------------- merge kernel: out = (O0 + O1) / (ll0 + ll1) for split rows --------
// Region: tokens [1024,2048) of each batch, all 2048 cols. 1,048,576 float4s.
__global__ __launch_bounds__(256) void k_merge(float* __restrict__ out,
                                               const float* __restrict__ out1,
                                               const float* __restrict__ ll0t,
                                               const float* __restrict__ ll1t) {
  const int idx = blockIdx.x * 256 + threadIdx.x;   // float4 index in region
  const int rp = idx >> 9;          // region row 0..2047 (b*1024 + tokoff)
  const int c4 = idx & 511;         // float4 col
  const int h = c4 >> 5;            // head (32 float4 per head)
  const int b = rp >> 10;
  const int tokoff = rp & 1023;
  const float lsum = ll0t[rp * 16 + h] + ll1t[rp * 16 + h];
  const float inv = 1.0f / lsum;
  float4* po = (float4*)(out + ((size_t)(b * 2048 + 1024 + tokoff)) * 2048) + c4;
  const float4* p1 = (const float4*)(out1 + (size_t)rp * 2048) + c4;
  const float4 o = *po;
  const float4 o1 = *p1;
  float4 w4;
  w4.x = (o.x + o1.x) * inv;
  w4.y = (o.y + o1.y) * inv;
  w4.z = (o.z + o1.z) * inv;
  w4.w = (o.w + o1.w) * inv;
  *po = w4;
}

extern "C" void kernel_launch(void* const* d_in, const int* in_sizes, int n_in,
                              void* d_out, int out_size, void* d_ws, size_t ws_size,
                              hipStream_t stream) {
  const float* x  = (const float*)d_in[0];
  const float* wq = (const float*)d_in[1];
  const float* wk = (const float*)d_in[2];
  const float* wv = (const float*)d_in[3];
  float* out = (float*)d_out;
  char* ws = (char*)d_ws;

  float* cost = (float*)(ws);                 // 512 KB
  float* sint = (float*)(ws + 524288);        // 512 KB
  u16* xb  = (u16*)(ws + 1048576);            // 16 MB
  u16* wqb = (u16*)(ws + 17825792);           // 8 MB
  u16* wkb = (u16*)(ws + 26214400);           // 2 MB
  u16* wvb = (u16*)(ws + 28311552);           // 2 MB
  u16* qb  = (u16*)(ws + 30408704);           // 16 MB
  u16* kb  = (u16*)(ws + 47185920);           // 4 MB
  u16* vT  = (u16*)(ws + 51380224);           // 4 MB  -> total 55574528
  if (ws_size < 55574528) return;

  // Reclaimed regions (dead after k_gemm / k_normrope):
  float* out1 = (float*)(ws + 1048576);       // xb region: O1 partials (16.78 MB exact)
  float* ll0t = (float*)(ws);                 // cost region: ll0 table (128 KB)
  float* ll1t = (float*)(ws + 524288);        // sint region: ll1 table (128 KB)

  k_tables  <<<dim3(512),   dim3(256), 0, stream>>>(cost, sint);
  k_convert <<<dim3(2048),  dim3(256), 0, stream>>>(x, wq, wk, wv, xb, wqb, wkb, wvb);
  k_gemm    <<<dim3(32, 24), dim3(256), 0, stream>>>(xb, wqb, wkb, wvb, qb, kb, vT);
  k_normrope<<<dim3(20480), dim3(256), 0, stream>>>(qb, kb, cost, sint);
  k_attn    <<<dim3(1536),  dim3(128), 0, stream>>>(qb, kb, vT, out, out1, ll0t, ll1t);
  k_merge   <<<dim3(4096),  dim3(256), 0, stream>>>(out, out1, ll0t, ll1t);
}

// Round 16
// 175.226 us; speedup vs baseline: 1.0145x; 1.0145x over previous
//
#include <hip/hip_runtime.h>
#include <hip/hip_bf16.h>
#include <cstdint>

typedef __bf16 bf16x8 __attribute__((ext_vector_type(8)));
typedef float f32x4 __attribute__((ext_vector_type(4)));
typedef float f32x16 __attribute__((ext_vector_type(16)));
typedef unsigned int u32;
typedef unsigned short u16;
typedef u32 u32x4 __attribute__((ext_vector_type(4)));

#define AS1 __attribute__((address_space(1)))
#define AS3 __attribute__((address_space(3)))

static __device__ __forceinline__ void gld16(const void* g, void* l) {
  __builtin_amdgcn_global_load_lds((const AS1 u32*)g, (AS3 u32*)l, 16, 0, 0);
}
static __device__ __forceinline__ u16 f2b(float f) {
  return __builtin_bit_cast(u16, __float2bfloat16(f));
}
static __device__ __forceinline__ float b2f(u16 u) {
  return __bfloat162float(__builtin_bit_cast(__hip_bfloat16, u));
}
// one-instruction pack: lo = bf16(a), hi = bf16(b)
static __device__ __forceinline__ u32 cvtpk(float a, float b) {
  u32 r;
  asm("v_cvt_pk_bf16_f32 %0, %1, %2" : "=v"(r) : "v"(a), "v"(b));
  return r;
}

// ---------------- RoPE tables: cos/sin[t][i], t<2048, i<64 ----------------
__global__ void k_tables(float* __restrict__ cost, float* __restrict__ sint) {
  const int idx = blockIdx.x * 256 + threadIdx.x;   // 131072 total
  const int t = idx >> 6, i = idx & 63;
  const float inv = exp2f(-(float)(2 * i) * (13.287712379549449f / 128.0f));
  const float f = (float)t * inv;
  cost[idx] = cosf(f);
  sint[idx] = sinf(f);
}

// ---------------- fp32 -> bf16 convert of x, Wq, Wk, Wv ----------------
__global__ void k_convert(const float* __restrict__ x, const float* __restrict__ wq,
                          const float* __restrict__ wk, const float* __restrict__ wv,
                          u16* __restrict__ xb, u16* __restrict__ wqb,
                          u16* __restrict__ wkb, u16* __restrict__ wvb) {
  for (int i4 = blockIdx.x * blockDim.x + threadIdx.x; i4 < 3670016;
       i4 += gridDim.x * blockDim.x) {
    const int e = i4 * 4;
    const float* s; u16* d;
    if (e < 8388608)        { s = x  + e;              d = xb  + e; }
    else if (e < 12582912)  { int o = e - 8388608;  s = wq + o; d = wqb + o; }
    else if (e < 13631488)  { int o = e - 12582912; s = wk + o; d = wkb + o; }
    else                    { int o = e - 13631488; s = wv + o; d = wvb + o; }
    const float4 v = *(const float4*)s;
    ushort4 o4;
    o4.x = f2b(v.x); o4.y = f2b(v.y); o4.z = f2b(v.z); o4.w = f2b(v.w);
    *(ushort4*)d = o4;
  }
}

// ---------------- fused QKV GEMM + RMSNorm + RoPE epilogue (q,k) ----------------
// Each q/k block computes one head x 128 tokens x all 128 dims -> norm scope is
// block-local. Epilogue: shfl+LDS sum-of-squares, swizzled LDS dim-pair exchange
// (d <-> d+64 lives on the partner wave at identical (nt,lm)), RoPE from tables,
// q pre-scaled by log2(e)/sqrt(128) (=> attention needs no scale and no max).
// vT written with token bits 2<->3 swapped (exchange-free PV in attention).
__global__ __launch_bounds__(256) void k_gemm(
    const u16* __restrict__ xb, const u16* __restrict__ wqb,
    const u16* __restrict__ wkb, const u16* __restrict__ wvb,
    const float* __restrict__ cost, const float* __restrict__ sint,
    u16* __restrict__ qb, u16* __restrict__ kb, u16* __restrict__ vT) {
  __shared__ __align__(16) char smBuf[16384];
  char* smA = smBuf;            // [128][32] bf16, source-chunk-swizzled
  char* smB = smBuf + 8192;
  const int tid = threadIdx.x;
  const int w = tid >> 6, l = tid & 63;
  const int lm = l & 15, g = l >> 4;
  const int m0 = blockIdx.x << 7;
  const int j = blockIdx.y;
  const u16* W; u16* dst; int n0, ldc, vmode;
  if (j < 16)      { W = wqb; dst = qb; n0 = j << 7;        ldc = 2048; vmode = 0; }
  else if (j < 20) { W = wkb; dst = kb; n0 = (j - 16) << 7; ldc = 512;  vmode = 0; }
  else             { W = wvb; dst = vT; n0 = (j - 20) << 7; ldc = 0;    vmode = 1; }

  const int srow = w * 16 + (l >> 2);
  const int scol = l & 3;

  f32x4 acc[4][4];
  #pragma unroll
  for (int a = 0; a < 4; ++a)
    #pragma unroll
    for (int bb = 0; bb < 4; ++bb) { f32x4 zz = {0.f, 0.f, 0.f, 0.f}; acc[a][bb] = zz; }

  const int wm = (w >> 1) << 6, wn = (w & 1) << 6;

  for (int k0 = 0; k0 < 2048; k0 += 32) {
    #pragma unroll
    for (int i = 0; i < 2; ++i) {
      const int r = srow + (i << 6);
      const int sc = (scol ^ (r & 3)) << 3;
      gld16(xb + (m0 + r) * 2048 + k0 + sc, smA + ((i * 4 + w) << 10));
      gld16(W  + (n0 + r) * 2048 + k0 + sc, smB + ((i * 4 + w) << 10));
    }
    __syncthreads();
    bf16x8 af[4], bfr[4];
    #pragma unroll
    for (int mt = 0; mt < 4; ++mt) {
      const int row = wm + mt * 16 + lm;
      af[mt] = *(const bf16x8*)(smA + row * 64 + ((g ^ (row & 3)) << 4));
    }
    #pragma unroll
    for (int nt = 0; nt < 4; ++nt) {
      const int row = wn + nt * 16 + lm;
      bfr[nt] = *(const bf16x8*)(smB + row * 64 + ((g ^ (row & 3)) << 4));
    }
    #pragma unroll
    for (int mt = 0; mt < 4; ++mt)
      #pragma unroll
      for (int nt = 0; nt < 4; ++nt)
        acc[mt][nt] = __builtin_amdgcn_mfma_f32_16x16x32_bf16(af[mt], bfr[nt], acc[mt][nt], 0, 0, 0);
    __syncthreads();
  }

  if (vmode) {
    // V: plain store, token bits 2<->3 swapped for attention's exchange-free PV
    const int gs = ((g & 1) << 1) | (g >> 1);
    #pragma unroll
    for (int mt = 0; mt < 4; ++mt)
      #pragma unroll
      for (int nt = 0; nt < 4; ++nt) {
        const int n = n0 + wn + nt * 16 + lm;
        #pragma unroll
        for (int r = 0; r < 4; ++r) {
          const int mv = m0 + wm + mt * 16 + gs * 4 + r;
          dst[n * 4096 + mv] = f2b(acc[mt][nt][r]);
        }
      }
    return;
  }

  // ---- fused RMSNorm + RoPE epilogue (q and k) ----
  // Step 1: per-token sum of squares over this wave's 64 dims
  float sh[4][4], rn[4][4];
  #pragma unroll
  for (int mt = 0; mt < 4; ++mt)
    #pragma unroll
    for (int r = 0; r < 4; ++r) {
      float p = acc[mt][0][r] * acc[mt][0][r] + acc[mt][1][r] * acc[mt][1][r]
              + acc[mt][2][r] * acc[mt][2][r] + acc[mt][3][r] * acc[mt][3][r];
      p += __shfl_xor(p, 1); p += __shfl_xor(p, 2);
      p += __shfl_xor(p, 4); p += __shfl_xor(p, 8);
      sh[mt][r] = p;
    }
  // Step 2: cross-wave (wn-pair) merge via 1KB LDS
  float* sm4 = (float*)smBuf;          // [4 waves][64 tokens]
  if (lm == 0) {
    #pragma unroll
    for (int mt = 0; mt < 4; ++mt)
      #pragma unroll
      for (int r = 0; r < 4; ++r)
        sm4[w * 64 + mt * 16 + g * 4 + r] = sh[mt][r];
  }
  __syncthreads();
  #pragma unroll
  for (int mt = 0; mt < 4; ++mt)
    #pragma unroll
    for (int r = 0; r < 4; ++r) {
      const float ss = sh[mt][r] + sm4[(w ^ 1) * 64 + mt * 16 + g * 4 + r];
      rn[mt][r] = rsqrtf(ss * (1.0f / 128.0f) + 1.1920928955078125e-07f);
    }
  const float qs = (j < 16) ? 0.12751742f : 1.0f;   // log2(e)/sqrt(128) for q
  const int wnH = w & 1;                             // 0: dims<64 (x1), 1: dims>=64 (x2)

  // Step 3: per-mt swizzled exchange of raw acc with partner wave + RoPE + store
  float* smX = (float*)smBuf;          // [4 waves][16 tl][64 i], i ^ (g<<4) swizzle
  #pragma unroll
  for (int mt = 0; mt < 4; ++mt) {
    __syncthreads();                   // previous phase reads done
    #pragma unroll
    for (int nt = 0; nt < 4; ++nt)
      #pragma unroll
      for (int r = 0; r < 4; ++r) {
        const int tl = g * 4 + r;
        const int iw = (nt * 16 + lm) ^ ((tl >> 2) << 4);
        smX[w * 1024 + tl * 64 + iw] = acc[mt][nt][r];
      }
    __syncthreads();
    #pragma unroll
    for (int nt = 0; nt < 4; ++nt) {
      const int i = nt * 16 + lm;
      #pragma unroll
      for (int r = 0; r < 4; ++r) {
        const int tl = g * 4 + r;
        const int iw = i ^ ((tl >> 2) << 4);
        const float part = smX[(w ^ 1) * 1024 + tl * 64 + iw];
        const float own  = acc[mt][nt][r];
        const int t = m0 + wm + mt * 16 + g * 4 + r;
        const int ti = (t & 2047) * 64 + i;
        const float c = cost[ti], s = sint[ti];
        // wave A (wnH=0): y1 = x1*c + x2*s ; wave B (wnH=1): y2 = x2*c - x1*s
        const float y = wnH ? (own * c - part * s) : (own * c + part * s);
        dst[(size_t)t * ldc + n0 + wn + nt * 16 + lm] = f2b(y * rn[mt][r] * qs);
      }
    }
  }
}

// ---------------- causal GQA flash attention: no-max softmax + kv-split, -------------
// ---------------- SINGLE-buffer 32KB LDS -> 4 blocks/CU (2 indep waves/SIMD) ---------
// grid (1024): bid&7 = (b,hkv) XCD-local. g = bid>>5 in [0,32), a = g&7.
// Ring-complementary tau map: ring0 31-a, ring1 16+a, ring2 15-a, ring3 a ->
// each CU's 4 resident blocks {bid, +256, +512, +768} sum to exactly 66
// double-rounds (balanced), longest dispatched first.
// Block = 64 q-rows (2 waves x 32 q). kv range split into two interleaved
// independent streams A/B (additive merge, m=0 softmax). PV B-fragments are the
// lane's own cvtpk'd P values (vT columns pre-permuted by token bit2<->3 swap).
__global__ __launch_bounds__(128) void k_attn(
    const u16* __restrict__ qb, const u16* __restrict__ kb,
    const u16* __restrict__ vT, float* __restrict__ out) {
  __shared__ __align__(16) char lds[32768];   // [stream][K 8K | V 8K]
  const int tid = threadIdx.x;
  const int l = tid & 63;
  const int w = tid >> 6;          // wave 0/1 -> q offset 32*w
  const int lq = l & 31;
  const int hi = l >> 5;

  const int bid = blockIdx.x;
  const int cxc = bid & 7;
  const int bb  = cxc >> 2, hkv = cxc & 3;
  const int hsub = (bid >> 3) & 3;
  const int h   = hkv * 4 + hsub;
  const int g   = bid >> 5;              // 0..31, ring = g>>3
  const int a   = g & 7;
  const int tau = (g < 8) ? (31 - a) : (g < 16) ? (16 + a) : (g < 24) ? (15 - a) : a;
  const int RH  = tau + 1;               // double-rounds (each = 2 kv-tiles of 32)
  const int half = RH * 32;              // stream B kv offset

  const u16* kbase = kb + ((size_t)bb * 2048) * 512 + hkv * 128;
  const u16* vbase = vT + ((size_t)(hkv * 128)) * 4096 + (size_t)bb * 2048;
  const u16* qhb   = qb + ((size_t)bb * 2048) * 2048 + h * 128;

  const int krow_t = tid >> 4, kch = tid & 15;   // K staging coords
  const int vrow_t = tid >> 2, vch = tid & 3;    // V staging coords

  const int qabs = tau * 64 + w * 32 + lq;
  const int qmin = tau * 64 + w * 32;

  bf16x8 qf[8];
  {
    const u16* qp = qhb + (size_t)qabs * 2048;
    #pragma unroll
    for (int c = 0; c < 8; ++c) qf[c] = *(const bf16x8*)(qp + c * 16 + hi * 8);
  }
  f32x16 oacc[4], sA, sB;
  #pragma unroll
  for (int dt = 0; dt < 4; ++dt)
    #pragma unroll
    for (int e = 0; e < 16; ++e) oacc[dt][e] = 0.f;
  float llA = 0.f, llB = 0.f;

  // stage one stream's kv-tile (16 KB: K 8K + V 8K), 128 threads x 8 gld16
  auto STAGE = [&](int st, int jb2) {
    char* bK = lds + st * 16384;
    char* bV = bK + 8192;
    #pragma unroll
    for (int u = 0; u < 4; ++u) {
      const int kr = u * 8 + krow_t;
      gld16(kbase + (size_t)(jb2 + kr) * 512 + ((kch ^ (kr & 15)) << 3),
            bK + u * 2048 + tid * 16);
      // V paired-row layout: slot (R0, C0) holds V[2*R0 + (cp>>2)][8*(cp&3) ..]
      const int R0 = u * 16 + (vrow_t >> 1);          // 0..63
      const int C0 = ((vrow_t & 1) << 2) + vch;       // 0..7
      const int cp = C0 ^ (R0 & 7);
      const int vd = 2 * R0 + (cp >> 2);              // d row 0..127
      gld16(vbase + (size_t)vd * 4096 + jb2 + ((cp & 3) << 3),
            bV + u * 2048 + tid * 16);
    }
  };

  STAGE(0, 0);
  STAGE(1, half);
  __syncthreads();

  for (int r = 0; r < RH; ++r) {
    // ---- QK^T for both streams (independent MFMA chains) ----
    #pragma unroll
    for (int e = 0; e < 16; ++e) { sA[e] = 0.f; sB[e] = 0.f; }
    const char* skA = lds;
    const char* skB = lds + 16384;
    #pragma unroll
    for (int c = 0; c < 8; ++c) {
      const int ch = ((2 * c + hi) ^ (lq & 15)) << 4;
      const bf16x8 kfA = *(const bf16x8*)(skA + lq * 256 + ch);
      const bf16x8 kfB = *(const bf16x8*)(skB + lq * 256 + ch);
      sA = __builtin_amdgcn_mfma_f32_32x32x16_bf16(kfA, qf[c], sA, 0, 0, 0);
      sB = __builtin_amdgcn_mfma_f32_32x32x16_bf16(kfB, qf[c], sB, 0, 0, 0);
    }

    // ---- no-max softmax: p = exp2(s) (|s| <= 16.4 by RMS-norm bound) ----
    const int jbA = r * 32;
    const int jbB = half + r * 32;
    if (jbA + 31 > qmin) {
      #pragma unroll
      for (int e = 0; e < 16; ++e) {
        const int kvl = (e & 3) + ((e >> 2) << 3) + (hi << 2);
        if (jbA + kvl > qabs) sA[e] = -1e30f;
      }
    }
    if (jbB + 31 > qmin) {
      #pragma unroll
      for (int e = 0; e < 16; ++e) {
        const int kvl = (e & 3) + ((e >> 2) << 3) + (hi << 2);
        if (jbB + kvl > qabs) sB[e] = -1e30f;
      }
    }
    float rA = 0.f, rB = 0.f;
    #pragma unroll
    for (int e = 0; e < 16; e += 4) {
      const float a0 = exp2f(sA[e]),     a1 = exp2f(sA[e + 1]);
      const float a2 = exp2f(sA[e + 2]), a3 = exp2f(sA[e + 3]);
      const float b0 = exp2f(sB[e]),     b1 = exp2f(sB[e + 1]);
      const float b2 = exp2f(sB[e + 2]), b3 = exp2f(sB[e + 3]);
      sA[e] = a0; sA[e + 1] = a1; sA[e + 2] = a2; sA[e + 3] = a3;
      sB[e] = b0; sB[e + 1] = b1; sB[e + 2] = b2; sB[e + 3] = b3;
      rA += (a0 + a1) + (a2 + a3);
      rB += (b0 + b1) + (b2 + b3);
    }
    llA += rA; llB += rB;

    // ---- PV for both streams into shared oacc (additive merge) ----
    // Exchange-free: B-fragment = lane's own P values in order (vT pre-permuted).
    const char* svA = lds + 8192;
    const char* svB = lds + 16384 + 8192;
    #pragma unroll
    for (int cc = 0; cc < 2; ++cc) {
      const int c8 = cc * 8;
      u32x4 bwA, bwB;
      bwA.x = cvtpk(sA[c8 + 0], sA[c8 + 1]);
      bwA.y = cvtpk(sA[c8 + 2], sA[c8 + 3]);
      bwA.z = cvtpk(sA[c8 + 4], sA[c8 + 5]);
      bwA.w = cvtpk(sA[c8 + 6], sA[c8 + 7]);
      bwB.x = cvtpk(sB[c8 + 0], sB[c8 + 1]);
      bwB.y = cvtpk(sB[c8 + 2], sB[c8 + 3]);
      bwB.z = cvtpk(sB[c8 + 4], sB[c8 + 5]);
      bwB.w = cvtpk(sB[c8 + 6], sB[c8 + 7]);
      const bf16x8 pfA = __builtin_bit_cast(bf16x8, bwA);
      const bf16x8 pfB = __builtin_bit_cast(bf16x8, bwB);
      #pragma unroll
      for (int dt = 0; dt < 4; ++dt) {
        const int vrow = dt * 16 + (lq >> 1);
        const int cpre = ((lq & 1) << 2) + 2 * cc + hi;
        const int chv = (cpre ^ (vrow & 7)) << 4;
        const bf16x8 vfA = *(const bf16x8*)(svA + vrow * 128 + chv);
        oacc[dt] = __builtin_amdgcn_mfma_f32_32x32x16_bf16(vfA, pfA, oacc[dt], 0, 0, 0);
      }
      #pragma unroll
      for (int dt = 0; dt < 4; ++dt) {
        const int vrow = dt * 16 + (lq >> 1);
        const int cpre = ((lq & 1) << 2) + 2 * cc + hi;
        const int chv = (cpre ^ (vrow & 7)) << 4;
        const bf16x8 vfB = *(const bf16x8*)(svB + vrow * 128 + chv);
        oacc[dt] = __builtin_amdgcn_mfma_f32_32x32x16_bf16(vfB, pfB, oacc[dt], 0, 0, 0);
      }
    }

    // ---- restage (single buffer): wait for readers, stage, wait for data ----
    if (r + 1 < RH) {
      __syncthreads();                 // all waves done reading this round
      STAGE(0, (r + 1) * 32);
      STAGE(1, half + (r + 1) * 32);
      __syncthreads();                 // vmcnt(0) drain + visibility
    }
  }

  // ---- epilogue: merge streams + halves, write O ----
  float ll = llA + llB;
  ll += __shfl_xor(ll, 32);
  const float inv = 1.0f / ll;
  float* ob = out + ((size_t)(bb * 2048 + qabs)) * 2048 + h * 128;
  #pragma unroll
  for (int dt = 0; dt < 4; ++dt)
    #pragma unroll
    for (int qd = 0; qd < 4; ++qd) {
      float4 o4;
      o4.x = oacc[dt][qd * 4 + 0] * inv;
      o4.y = oacc[dt][qd * 4 + 1] * inv;
      o4.z = oacc[dt][qd * 4 + 2] * inv;
      o4.w = oacc[dt][qd * 4 + 3] * inv;
      *(float4*)(ob + dt * 32 + qd * 8 + hi * 4) = o4;
    }
}

extern "C" void kernel_launch(void* const* d_in, const int* in_sizes, int n_in,
                              void* d_out, int out_size, void* d_ws, size_t ws_size,
                              hipStream_t stream) {
  const float* x  = (const float*)d_in[0];
  const float* wq = (const float*)d_in[1];
  const float* wk = (const float*)d_in[2];
  const float* wv = (const float*)d_in[3];
  float* out = (float*)d_out;
  char* ws = (char*)d_ws;

  float* cost = (float*)(ws);                 // 512 KB
  float* sint = (float*)(ws + 524288);        // 512 KB
  u16* xb  = (u16*)(ws + 1048576);            // 16 MB
  u16* wqb = (u16*)(ws + 17825792);           // 8 MB
  u16* wkb = (u16*)(ws + 26214400);           // 2 MB
  u16* wvb = (u16*)(ws + 28311552);           // 2 MB
  u16* qb  = (u16*)(ws + 30408704);           // 16 MB
  u16* kb  = (u16*)(ws + 47185920);           // 4 MB
  u16* vT  = (u16*)(ws + 51380224);           // 4 MB  -> total 55574528
  if (ws_size < 55574528) return;

  k_tables  <<<dim3(512),   dim3(256), 0, stream>>>(cost, sint);
  k_convert <<<dim3(2048),  dim3(256), 0, stream>>>(x, wq, wk, wv, xb, wqb, wkb, wvb);
  k_gemm    <<<dim3(32, 24), dim3(256), 0, stream>>>(xb, wqb, wkb, wvb, cost, sint,
                                                     qb, kb, vT);
  k_attn    <<<dim3(1024),  dim3(128), 0, stream>>>(qb, kb, vT, out);
}

// Round 17
// 174.893 us; speedup vs baseline: 1.0165x; 1.0019x over previous
//
#include <hip/hip_runtime.h>
#include <hip/hip_bf16.h>
#include <cstdint>

typedef __bf16 bf16x8 __attribute__((ext_vector_type(8)));
typedef float f32x4 __attribute__((ext_vector_type(4)));
typedef float f32x16 __attribute__((ext_vector_type(16)));
typedef unsigned int u32;
typedef unsigned short u16;
typedef u32 u32x4 __attribute__((ext_vector_type(4)));

#define AS1 __attribute__((address_space(1)))
#define AS3 __attribute__((address_space(3)))

static __device__ __forceinline__ void gld16(const void* g, void* l) {
  __builtin_amdgcn_global_load_lds((const AS1 u32*)g, (AS3 u32*)l, 16, 0, 0);
}
static __device__ __forceinline__ u16 f2b(float f) {
  return __builtin_bit_cast(u16, __float2bfloat16(f));
}
static __device__ __forceinline__ float b2f(u16 u) {
  return __bfloat162float(__builtin_bit_cast(__hip_bfloat16, u));
}
// one-instruction pack: lo = bf16(a), hi = bf16(b)
static __device__ __forceinline__ u32 cvtpk(float a, float b) {
  u32 r;
  asm("v_cvt_pk_bf16_f32 %0, %1, %2" : "=v"(r) : "v"(a), "v"(b));
  return r;
}

// ---------------- RoPE tables: cos/sin[t][i], t<2048, i<64 ----------------
__global__ void k_tables(float* __restrict__ cost, float* __restrict__ sint) {
  const int idx = blockIdx.x * 256 + threadIdx.x;   // 131072 total
  const int t = idx >> 6, i = idx & 63;
  const float inv = exp2f(-(float)(2 * i) * (13.287712379549449f / 128.0f));
  const float f = (float)t * inv;
  cost[idx] = cosf(f);
  sint[idx] = sinf(f);
}

// ---------------- fp32 -> bf16 convert of x, Wq, Wk, Wv ----------------
__global__ void k_convert(const float* __restrict__ x, const float* __restrict__ wq,
                          const float* __restrict__ wk, const float* __restrict__ wv,
                          u16* __restrict__ xb, u16* __restrict__ wqb,
                          u16* __restrict__ wkb, u16* __restrict__ wvb) {
  for (int i4 = blockIdx.x * blockDim.x + threadIdx.x; i4 < 3670016;
       i4 += gridDim.x * blockDim.x) {
    const int e = i4 * 4;
    const float* s; u16* d;
    if (e < 8388608)        { s = x  + e;              d = xb  + e; }
    else if (e < 12582912)  { int o = e - 8388608;  s = wq + o; d = wqb + o; }
    else if (e < 13631488)  { int o = e - 12582912; s = wk + o; d = wkb + o; }
    else                    { int o = e - 13631488; s = wv + o; d = wvb + o; }
    const float4 v = *(const float4*)s;
    ushort4 o4;
    o4.x = f2b(v.x); o4.y = f2b(v.y); o4.z = f2b(v.z); o4.w = f2b(v.w);
    *(ushort4*)d = o4;
  }
}

// ---------------- fused QKV GEMM + RMSNorm + RoPE epilogue (q,k) ----------------
// Fragment-column remap: wave w owns cols {c..c+31} U {c+64..c+95}, c = 32*(w&1)
// (fragments nt -> col base colmap(nt) = 32*(w&1) + 16*(nt&1) + 64*(nt>>1)).
// RoPE pair (i, i+64) = fragments (nt, nt+2): IN-REGISTER, no LDS exchange.
// Norm: wave-local shfl sum over 64 cols + 1-barrier sm4 merge with wave w^1.
// q pre-scaled by log2(e)/sqrt(128) => attention needs no scale, no max.
// vT written with token bits 2<->3 swapped (exchange-free PV in attention).
__global__ __launch_bounds__(256) void k_gemm(
    const u16* __restrict__ xb, const u16* __restrict__ wqb,
    const u16* __restrict__ wkb, const u16* __restrict__ wvb,
    const float* __restrict__ cost, const float* __restrict__ sint,
    u16* __restrict__ qb, u16* __restrict__ kb, u16* __restrict__ vT) {
  __shared__ __align__(16) char smA[8192];   // [128][32] bf16, source-chunk-swizzled
  __shared__ __align__(16) char smB[8192];
  __shared__ float sm4[4][64];
  const int tid = threadIdx.x;
  const int w = tid >> 6, l = tid & 63;
  const int lm = l & 15, g = l >> 4;
  const int m0 = blockIdx.x << 7;
  const int j = blockIdx.y;
  const u16* W; u16* dst; int n0, ldc, vmode;
  if (j < 16)      { W = wqb; dst = qb; n0 = j << 7;        ldc = 2048; vmode = 0; }
  else if (j < 20) { W = wkb; dst = kb; n0 = (j - 16) << 7; ldc = 512;  vmode = 0; }
  else             { W = wvb; dst = vT; n0 = (j - 20) << 7; ldc = 0;    vmode = 1; }

  const int srow = w * 16 + (l >> 2);
  const int scol = l & 3;

  f32x4 acc[4][4];
  #pragma unroll
  for (int a = 0; a < 4; ++a)
    #pragma unroll
    for (int bb = 0; bb < 4; ++bb) { f32x4 zz = {0.f, 0.f, 0.f, 0.f}; acc[a][bb] = zz; }

  const int wm = (w >> 1) << 6;
  // column base for fragment nt: 32*(w&1) + 16*(nt&1) + 64*(nt>>1)
  const int cw = (w & 1) << 5;

  for (int k0 = 0; k0 < 2048; k0 += 32) {
    #pragma unroll
    for (int i = 0; i < 2; ++i) {
      const int r = srow + (i << 6);
      const int sc = (scol ^ (r & 3)) << 3;
      gld16(xb + (m0 + r) * 2048 + k0 + sc, smA + ((i * 4 + w) << 10));
      gld16(W  + (n0 + r) * 2048 + k0 + sc, smB + ((i * 4 + w) << 10));
    }
    __syncthreads();
    bf16x8 af[4], bfr[4];
    #pragma unroll
    for (int mt = 0; mt < 4; ++mt) {
      const int row = wm + mt * 16 + lm;
      af[mt] = *(const bf16x8*)(smA + row * 64 + ((g ^ (row & 3)) << 4));
    }
    #pragma unroll
    for (int nt = 0; nt < 4; ++nt) {
      const int row = cw + ((nt & 1) << 4) + ((nt >> 1) << 6) + lm;
      bfr[nt] = *(const bf16x8*)(smB + row * 64 + ((g ^ (row & 3)) << 4));
    }
    #pragma unroll
    for (int mt = 0; mt < 4; ++mt)
      #pragma unroll
      for (int nt = 0; nt < 4; ++nt)
        acc[mt][nt] = __builtin_amdgcn_mfma_f32_16x16x32_bf16(af[mt], bfr[nt], acc[mt][nt], 0, 0, 0);
    __syncthreads();
  }

  if (vmode) {
    // V: plain store, token bits 2<->3 swapped for attention's exchange-free PV
    const int gs = ((g & 1) << 1) | (g >> 1);
    #pragma unroll
    for (int mt = 0; mt < 4; ++mt)
      #pragma unroll
      for (int nt = 0; nt < 4; ++nt) {
        const int n = n0 + cw + ((nt & 1) << 4) + ((nt >> 1) << 6) + lm;
        #pragma unroll
        for (int r = 0; r < 4; ++r) {
          const int mv = m0 + wm + mt * 16 + gs * 4 + r;
          dst[n * 4096 + mv] = f2b(acc[mt][nt][r]);
        }
      }
    return;
  }

  // ---- fused RMSNorm + RoPE epilogue (q and k), exchange-free ----
  // Step 1: per-token sum of squares over this wave's 64 cols
  float sh[4][4], rn[4][4];
  #pragma unroll
  for (int mt = 0; mt < 4; ++mt)
    #pragma unroll
    for (int r = 0; r < 4; ++r) {
      float p = acc[mt][0][r] * acc[mt][0][r] + acc[mt][1][r] * acc[mt][1][r]
              + acc[mt][2][r] * acc[mt][2][r] + acc[mt][3][r] * acc[mt][3][r];
      p += __shfl_xor(p, 1); p += __shfl_xor(p, 2);
      p += __shfl_xor(p, 4); p += __shfl_xor(p, 8);
      sh[mt][r] = p;
    }
  // Step 2: cross-wave (w^1 = other col-parity) merge via 1KB LDS
  if (lm == 0) {
    #pragma unroll
    for (int mt = 0; mt < 4; ++mt)
      #pragma unroll
      for (int r = 0; r < 4; ++r)
        sm4[w][mt * 16 + g * 4 + r] = sh[mt][r];
  }
  __syncthreads();
  #pragma unroll
  for (int mt = 0; mt < 4; ++mt)
    #pragma unroll
    for (int r = 0; r < 4; ++r) {
      const float ss = sh[mt][r] + sm4[w ^ 1][mt * 16 + g * 4 + r];
      rn[mt][r] = rsqrtf(ss * (1.0f / 128.0f) + 1.1920928955078125e-07f);
    }
  const float qs = (j < 16) ? 0.12751742f : 1.0f;   // log2(e)/sqrt(128) for q

  // Step 3: in-register RoPE (pair = fragments nt, nt+2) + store
  #pragma unroll
  for (int mt = 0; mt < 4; ++mt) {
    #pragma unroll
    for (int nt = 0; nt < 2; ++nt) {
      const int i = cw + (nt << 4) + lm;           // 0..63
      #pragma unroll
      for (int r = 0; r < 4; ++r) {
        const int t = m0 + wm + mt * 16 + g * 4 + r;
        const int ti = (t & 2047) * 64 + i;
        const float c = cost[ti], s = sint[ti];
        const float xlo = acc[mt][nt][r];
        const float xhi = acc[mt][nt + 2][r];
        const float sc2 = rn[mt][r] * qs;
        dst[(size_t)t * ldc + n0 + i]      = f2b((xlo * c + xhi * s) * sc2);
        dst[(size_t)t * ldc + n0 + i + 64] = f2b((xhi * c - xlo * s) * sc2);
      }
    }
  }
}

// ---------------- causal GQA flash attention: no-max softmax + kv-split, -------------
// ---------------- SINGLE-buffer 32KB LDS -> 4 blocks/CU (2 indep waves/SIMD) ---------
// grid (1024): bid&7 = (b,hkv) XCD-local. g = bid>>5 in [0,32), a = g&7.
// Ring-complementary tau map: ring0 31-a, ring1 16+a, ring2 15-a, ring3 a ->
// each CU's 4 resident blocks {bid, +256, +512, +768} sum to exactly 66
// double-rounds (balanced), longest dispatched first.
// Block = 64 q-rows (2 waves x 32 q). kv range split into two interleaved
// independent streams A/B (additive merge, m=0 softmax). PV B-fragments are the
// lane's own cvtpk'd P values (vT columns pre-permuted by token bit2<->3 swap).
__global__ __launch_bounds__(128) void k_attn(
    const u16* __restrict__ qb, const u16* __restrict__ kb,
    const u16* __restrict__ vT, float* __restrict__ out) {
  __shared__ __align__(16) char lds[32768];   // [stream][K 8K | V 8K]
  const int tid = threadIdx.x;
  const int l = tid & 63;
  const int w = tid >> 6;          // wave 0/1 -> q offset 32*w
  const int lq = l & 31;
  const int hi = l >> 5;

  const int bid = blockIdx.x;
  const int cxc = bid & 7;
  const int bb  = cxc >> 2, hkv = cxc & 3;
  const int hsub = (bid >> 3) & 3;
  const int h   = hkv * 4 + hsub;
  const int g   = bid >> 5;              // 0..31, ring = g>>3
  const int a   = g & 7;
  const int tau = (g < 8) ? (31 - a) : (g < 16) ? (16 + a) : (g < 24) ? (15 - a) : a;
  const int RH  = tau + 1;               // double-rounds (each = 2 kv-tiles of 32)
  const int half = RH * 32;              // stream B kv offset

  const u16* kbase = kb + ((size_t)bb * 2048) * 512 + hkv * 128;
  const u16* vbase = vT + ((size_t)(hkv * 128)) * 4096 + (size_t)bb * 2048;
  const u16* qhb   = qb + ((size_t)bb * 2048) * 2048 + h * 128;

  const int krow_t = tid >> 4, kch = tid & 15;   // K staging coords
  const int vrow_t = tid >> 2, vch = tid & 3;    // V staging coords

  const int qabs = tau * 64 + w * 32 + lq;
  const int qmin = tau * 64 + w * 32;

  bf16x8 qf[8];
  {
    const u16* qp = qhb + (size_t)qabs * 2048;
    #pragma unroll
    for (int c = 0; c < 8; ++c) qf[c] = *(const bf16x8*)(qp + c * 16 + hi * 8);
  }
  f32x16 oacc[4], sA, sB;
  #pragma unroll
  for (int dt = 0; dt < 4; ++dt)
    #pragma unroll
    for (int e = 0; e < 16; ++e) oacc[dt][e] = 0.f;
  float llA = 0.f, llB = 0.f;

  // stage one stream's kv-tile (16 KB: K 8K + V 8K), 128 threads x 8 gld16
  auto STAGE = [&](int st, int jb2) {
    char* bK = lds + st * 16384;
    char* bV = bK + 8192;
    #pragma unroll
    for (int u = 0; u < 4; ++u) {
      const int kr = u * 8 + krow_t;
      gld16(kbase + (size_t)(jb2 + kr) * 512 + ((kch ^ (kr & 15)) << 3),
            bK + u * 2048 + tid * 16);
      // V paired-row layout: slot (R0, C0) holds V[2*R0 + (cp>>2)][8*(cp&3) ..]
      const int R0 = u * 16 + (vrow_t >> 1);          // 0..63
      const int C0 = ((vrow_t & 1) << 2) + vch;       // 0..7
      const int cp = C0 ^ (R0 & 7);
      const int vd = 2 * R0 + (cp >> 2);              // d row 0..127
      gld16(vbase + (size_t)vd * 4096 + jb2 + ((cp & 3) << 3),
            bV + u * 2048 + tid * 16);
    }
  };

  STAGE(0, 0);
  STAGE(1, half);
  __syncthreads();

  for (int r = 0; r < RH; ++r) {
    // ---- QK^T for both streams (independent MFMA chains) ----
    #pragma unroll
    for (int e = 0; e < 16; ++e) { sA[e] = 0.f; sB[e] = 0.f; }
    const char* skA = lds;
    const char* skB = lds + 16384;
    #pragma unroll
    for (int c = 0; c < 8; ++c) {
      const int ch = ((2 * c + hi) ^ (lq & 15)) << 4;
      const bf16x8 kfA = *(const bf16x8*)(skA + lq * 256 + ch);
      const bf16x8 kfB = *(const bf16x8*)(skB + lq * 256 + ch);
      sA = __builtin_amdgcn_mfma_f32_32x32x16_bf16(kfA, qf[c], sA, 0, 0, 0);
      sB = __builtin_amdgcn_mfma_f32_32x32x16_bf16(kfB, qf[c], sB, 0, 0, 0);
    }

    // ---- no-max softmax: p = exp2(s) (|s| <= 16.4 by RMS-norm bound) ----
    const int jbA = r * 32;
    const int jbB = half + r * 32;
    if (jbA + 31 > qmin) {
      #pragma unroll
      for (int e = 0; e < 16; ++e) {
        const int kvl = (e & 3) + ((e >> 2) << 3) + (hi << 2);
        if (jbA + kvl > qabs) sA[e] = -1e30f;
      }
    }
    if (jbB + 31 > qmin) {
      #pragma unroll
      for (int e = 0; e < 16; ++e) {
        const int kvl = (e & 3) + ((e >> 2) << 3) + (hi << 2);
        if (jbB + kvl > qabs) sB[e] = -1e30f;
      }
    }
    float rA = 0.f, rB = 0.f;
    #pragma unroll
    for (int e = 0; e < 16; e += 4) {
      const float a0 = exp2f(sA[e]),     a1 = exp2f(sA[e + 1]);
      const float a2 = exp2f(sA[e + 2]), a3 = exp2f(sA[e + 3]);
      const float b0 = exp2f(sB[e]),     b1 = exp2f(sB[e + 1]);
      const float b2 = exp2f(sB[e + 2]), b3 = exp2f(sB[e + 3]);
      sA[e] = a0; sA[e + 1] = a1; sA[e + 2] = a2; sA[e + 3] = a3;
      sB[e] = b0; sB[e + 1] = b1; sB[e + 2] = b2; sB[e + 3] = b3;
      rA += (a0 + a1) + (a2 + a3);
      rB += (b0 + b1) + (b2 + b3);
    }
    llA += rA; llB += rB;

    // ---- PV for both streams into shared oacc (additive merge) ----
    // Exchange-free: B-fragment = lane's own P values in order (vT pre-permuted).
    const char* svA = lds + 8192;
    const char* svB = lds + 16384 + 8192;
    #pragma unroll
    for (int cc = 0; cc < 2; ++cc) {
      const int c8 = cc * 8;
      u32x4 bwA, bwB;
      bwA.x = cvtpk(sA[c8 + 0], sA[c8 + 1]);
      bwA.y = cvtpk(sA[c8 + 2], sA[c8 + 3]);
      bwA.z = cvtpk(sA[c8 + 4], sA[c8 + 5]);
      bwA.w = cvtpk(sA[c8 + 6], sA[c8 + 7]);
      bwB.x = cvtpk(sB[c8 + 0], sB[c8 + 1]);
      bwB.y = cvtpk(sB[c8 + 2], sB[c8 + 3]);
      bwB.z = cvtpk(sB[c8 + 4], sB[c8 + 5]);
      bwB.w = cvtpk(sB[c8 + 6], sB[c8 + 7]);
      const bf16x8 pfA = __builtin_bit_cast(bf16x8, bwA);
      const bf16x8 pfB = __builtin_bit_cast(bf16x8, bwB);
      #pragma unroll
      for (int dt = 0; dt < 4; ++dt) {
        const int vrow = dt * 16 + (lq >> 1);
        const int cpre = ((lq & 1) << 2) + 2 * cc + hi;
        const int chv = (cpre ^ (vrow & 7)) << 4;
        const bf16x8 vfA = *(const bf16x8*)(svA + vrow * 128 + chv);
        oacc[dt] = __builtin_amdgcn_mfma_f32_32x32x16_bf16(vfA, pfA, oacc[dt], 0, 0, 0);
      }
      #pragma unroll
      for (int dt = 0; dt < 4; ++dt) {
        const int vrow = dt * 16 + (lq >> 1);
        const int cpre = ((lq & 1) << 2) + 2 * cc + hi;
        const int chv = (cpre ^ (vrow & 7)) << 4;
        const bf16x8 vfB = *(const bf16x8*)(svB + vrow * 128 + chv);
        oacc[dt] = __builtin_amdgcn_mfma_f32_32x32x16_bf16(vfB, pfB, oacc[dt], 0, 0, 0);
      }
    }

    // ---- restage (single buffer): wait for readers, stage, wait for data ----
    if (r + 1 < RH) {
      __syncthreads();                 // all waves done reading this round
      STAGE(0, (r + 1) * 32);
      STAGE(1, half + (r + 1) * 32);
      __syncthreads();                 // vmcnt(0) drain + visibility
    }
  }

  // ---- epilogue: merge streams + halves, write O ----
  float ll = llA + llB;
  ll += __shfl_xor(ll, 32);
  const float inv = 1.0f / ll;
  float* ob = out + ((size_t)(bb * 2048 + qabs)) * 2048 + h * 128;
  #pragma unroll
  for (int dt = 0; dt < 4; ++dt)
    #pragma unroll
    for (int qd = 0; qd < 4; ++qd) {
      float4 o4;
      o4.x = oacc[dt][qd * 4 + 0] * inv;
      o4.y = oacc[dt][qd * 4 + 1] * inv;
      o4.z = oacc[dt][qd * 4 + 2] * inv;
      o4.w = oacc[dt][qd * 4 + 3] * inv;
      *(float4*)(ob + dt * 32 + qd * 8 + hi * 4) = o4;
    }
}

extern "C" void kernel_launch(void* const* d_in, const int* in_sizes, int n_in,
                              void* d_out, int out_size, void* d_ws, size_t ws_size,
                              hipStream_t stream) {
  const float* x  = (const float*)d_in[0];
  const float* wq = (const float*)d_in[1];
  const float* wk = (const float*)d_in[2];
  const float* wv = (const float*)d_in[3];
  float* out = (float*)d_out;
  char* ws = (char*)d_ws;

  float* cost = (float*)(ws);                 // 512 KB
  float* sint = (float*)(ws + 524288);        // 512 KB
  u16* xb  = (u16*)(ws + 1048576);            // 16 MB
  u16* wqb = (u16*)(ws + 17825792);           // 8 MB
  u16* wkb = (u16*)(ws + 26214400);           // 2 MB
  u16* wvb = (u16*)(ws + 28311552);           // 2 MB
  u16* qb  = (u16*)(ws + 30408704);           // 16 MB
  u16* kb  = (u16*)(ws + 47185920);           // 4 MB
  u16* vT  = (u16*)(ws + 51380224);           // 4 MB  -> total 55574528
  if (ws_size < 55574528) return;

  k_tables  <<<dim3(512),   dim3(256), 0, stream>>>(cost, sint);
  k_convert <<<dim3(2048),  dim3(256), 0, stream>>>(x, wq, wk, wv, xb, wqb, wkb, wvb);
  k_gemm    <<<dim3(32, 24), dim3(256), 0, stream>>>(xb, wqb, wkb, wvb, cost, sint,
                                                     qb, kb, vT);
  k_attn    <<<dim3(1024),  dim3(128), 0, stream>>>(qb, kb, vT, out);
}

// Round 18
// 164.714 us; speedup vs baseline: 1.0793x; 1.0618x over previous
//
#include <hip/hip_runtime.h>
#include <hip/hip_bf16.h>
#include <cstdint>

typedef __bf16 bf16x8 __attribute__((ext_vector_type(8)));
typedef float f32x4 __attribute__((ext_vector_type(4)));
typedef float f32x16 __attribute__((ext_vector_type(16)));
typedef unsigned int u32;
typedef unsigned short u16;
typedef u32 u32x4 __attribute__((ext_vector_type(4)));

#define AS1 __attribute__((address_space(1)))
#define AS3 __attribute__((address_space(3)))

static __device__ __forceinline__ void gld16(const void* g, void* l) {
  __builtin_amdgcn_global_load_lds((const AS1 u32*)g, (AS3 u32*)l, 16, 0, 0);
}
static __device__ __forceinline__ u16 f2b(float f) {
  return __builtin_bit_cast(u16, __float2bfloat16(f));
}
static __device__ __forceinline__ float b2f(u16 u) {
  return __bfloat162float(__builtin_bit_cast(__hip_bfloat16, u));
}
// one-instruction pack: lo = bf16(a), hi = bf16(b)
static __device__ __forceinline__ u32 cvtpk(float a, float b) {
  u32 r;
  asm("v_cvt_pk_bf16_f32 %0, %1, %2" : "=v"(r) : "v"(a), "v"(b));
  return r;
}

// ---------------- RoPE tables: cos/sin[t][i], t<2048, i<64 ----------------
__global__ void k_tables(float* __restrict__ cost, float* __restrict__ sint) {
  const int idx = blockIdx.x * 256 + threadIdx.x;   // 131072 total
  const int t = idx >> 6, i = idx & 63;
  const float inv = exp2f(-(float)(2 * i) * (13.287712379549449f / 128.0f));
  const float f = (float)t * inv;
  cost[idx] = cosf(f);
  sint[idx] = sinf(f);
}

// ---------------- fp32 -> bf16 convert of x, Wq, Wk, Wv ----------------
__global__ void k_convert(const float* __restrict__ x, const float* __restrict__ wq,
                          const float* __restrict__ wk, const float* __restrict__ wv,
                          u16* __restrict__ xb, u16* __restrict__ wqb,
                          u16* __restrict__ wkb, u16* __restrict__ wvb) {
  for (int i4 = blockIdx.x * blockDim.x + threadIdx.x; i4 < 3670016;
       i4 += gridDim.x * blockDim.x) {
    const int e = i4 * 4;
    const float* s; u16* d;
    if (e < 8388608)        { s = x  + e;              d = xb  + e; }
    else if (e < 12582912)  { int o = e - 8388608;  s = wq + o; d = wqb + o; }
    else if (e < 13631488)  { int o = e - 12582912; s = wk + o; d = wkb + o; }
    else                    { int o = e - 13631488; s = wv + o; d = wvb + o; }
    const float4 v = *(const float4*)s;
    ushort4 o4;
    o4.x = f2b(v.x); o4.y = f2b(v.y); o4.z = f2b(v.z); o4.w = f2b(v.w);
    *(ushort4*)d = o4;
  }
}

// ---------------- fused QKV projection GEMM (bf16 MFMA, m97 structure) ----------------
// vT is written with token-index bits 2<->3 swapped (within each 16-token group):
// makes attention's PV B-fragment equal the lane's OWN softmax values (no shfl).
__global__ __launch_bounds__(256) void k_gemm(
    const u16* __restrict__ xb, const u16* __restrict__ wqb,
    const u16* __restrict__ wkb, const u16* __restrict__ wvb,
    u16* __restrict__ qb, u16* __restrict__ kb, u16* __restrict__ vT) {
  __shared__ __align__(16) char smA[8192];   // [128][32] bf16, source-chunk-swizzled
  __shared__ __align__(16) char smB[8192];
  const int tid = threadIdx.x;
  const int w = tid >> 6, l = tid & 63;
  const int lm = l & 15, g = l >> 4;
  const int m0 = blockIdx.x << 7;
  const int j = blockIdx.y;
  const u16* W; u16* dst; int n0, ldc, vmode;
  if (j < 16)      { W = wqb; dst = qb; n0 = j << 7;        ldc = 2048; vmode = 0; }
  else if (j < 20) { W = wkb; dst = kb; n0 = (j - 16) << 7; ldc = 512;  vmode = 0; }
  else             { W = wvb; dst = vT; n0 = (j - 20) << 7; ldc = 0;    vmode = 1; }

  const int srow = w * 16 + (l >> 2);
  const int scol = l & 3;

  f32x4 acc[4][4];
  #pragma unroll
  for (int a = 0; a < 4; ++a)
    #pragma unroll
    for (int bb = 0; bb < 4; ++bb) { f32x4 zz = {0.f, 0.f, 0.f, 0.f}; acc[a][bb] = zz; }

  const int wm = (w >> 1) << 6, wn = (w & 1) << 6;

  for (int k0 = 0; k0 < 2048; k0 += 32) {
    #pragma unroll
    for (int i = 0; i < 2; ++i) {
      const int r = srow + (i << 6);
      const int sc = (scol ^ (r & 3)) << 3;
      gld16(xb + (m0 + r) * 2048 + k0 + sc, smA + ((i * 4 + w) << 10));
      gld16(W  + (n0 + r) * 2048 + k0 + sc, smB + ((i * 4 + w) << 10));
    }
    __syncthreads();
    bf16x8 af[4], bfr[4];
    #pragma unroll
    for (int mt = 0; mt < 4; ++mt) {
      const int row = wm + mt * 16 + lm;
      af[mt] = *(const bf16x8*)(smA + row * 64 + ((g ^ (row & 3)) << 4));
    }
    #pragma unroll
    for (int nt = 0; nt < 4; ++nt) {
      const int row = wn + nt * 16 + lm;
      bfr[nt] = *(const bf16x8*)(smB + row * 64 + ((g ^ (row & 3)) << 4));
    }
    #pragma unroll
    for (int mt = 0; mt < 4; ++mt)
      #pragma unroll
      for (int nt = 0; nt < 4; ++nt)
        acc[mt][nt] = __builtin_amdgcn_mfma_f32_16x16x32_bf16(af[mt], bfr[nt], acc[mt][nt], 0, 0, 0);
    __syncthreads();
  }

  const int gs = ((g & 1) << 1) | (g >> 1);   // token-index bit2<->bit3 swap for vT
  #pragma unroll
  for (int mt = 0; mt < 4; ++mt) {
    #pragma unroll
    for (int nt = 0; nt < 4; ++nt) {
      const int n = n0 + wn + nt * 16 + lm;
      #pragma unroll
      for (int r = 0; r < 4; ++r) {
        const u16 hv = f2b(acc[mt][nt][r]);
        if (!vmode) {
          const int mq = m0 + wm + mt * 16 + g * 4 + r;
          dst[mq * ldc + n] = hv;
        } else {
          const int mv = m0 + wm + mt * 16 + gs * 4 + r;
          dst[n * 4096 + mv] = hv;
        }
      }
    }
  }
}

// ---------------- RMSNorm + RoPE in-place on q and k ----------------
// q additionally pre-scaled by log2(e)/sqrt(128) so attention skips the scale.
// Consequence: attention scores s in [-16.4, 16.4] -> no online max needed.
__global__ __launch_bounds__(256) void k_normrope(u16* __restrict__ qb, u16* __restrict__ kb,
                                                  const float* __restrict__ cost,
                                                  const float* __restrict__ sint) {
  const int item = blockIdx.x * 4 + (threadIdx.x >> 6);
  const int l = threadIdx.x & 63;
  u16* p; int tpos; float qs;
  if (item < 65536) { p = qb + item * 128; tpos = (item >> 4) & 2047; qs = 0.12751742f; }
  else { const int ik = item - 65536; p = kb + ik * 128; tpos = (ik >> 2) & 2047; qs = 1.0f; }
  const float f1 = b2f(p[l]);
  const float f2 = b2f(p[l + 64]);
  float ss = f1 * f1 + f2 * f2;
  #pragma unroll
  for (int d = 1; d < 64; d <<= 1) ss += __shfl_xor(ss, d);
  const float rn = rsqrtf(ss * (1.0f / 128.0f) + 1.1920928955078125e-07f);
  const float c = cost[tpos * 64 + l], s = sint[tpos * 64 + l];
  const float x1 = f1 * rn, x2 = f2 * rn;
  p[l]      = f2b((x1 * c + x2 * s) * qs);
  p[l + 64] = f2b((x2 * c - x1 * s) * qs);
}

// ---------------- causal GQA flash attention: no-max softmax + kv-split, -------------
// ---------------- SINGLE-buffer 32KB LDS -> 4 blocks/CU (2 indep waves/SIMD) ---------
// grid (1024): bid&7 = (b,hkv) XCD-local. g = bid>>5 in [0,32), a = g&7.
// Ring-complementary tau map: ring0 31-a, ring1 16+a, ring2 15-a, ring3 a ->
// each CU's 4 resident blocks {bid, +256, +512, +768} sum to exactly 66
// double-rounds (balanced), longest dispatched first.
// Block = 64 q-rows (2 waves x 32 q). kv range split into two interleaved
// independent streams A/B (additive merge, m=0 softmax). PV B-fragments are the
// lane's own cvtpk'd P values (vT columns pre-permuted by token bit2<->3 swap).
__global__ __launch_bounds__(128) void k_attn(
    const u16* __restrict__ qb, const u16* __restrict__ kb,
    const u16* __restrict__ vT, float* __restrict__ out) {
  __shared__ __align__(16) char lds[32768];   // [stream][K 8K | V 8K]
  const int tid = threadIdx.x;
  const int l = tid & 63;
  const int w = tid >> 6;          // wave 0/1 -> q offset 32*w
  const int lq = l & 31;
  const int hi = l >> 5;

  const int bid = blockIdx.x;
  const int cxc = bid & 7;
  const int bb  = cxc >> 2, hkv = cxc & 3;
  const int hsub = (bid >> 3) & 3;
  const int h   = hkv * 4 + hsub;
  const int g   = bid >> 5;              // 0..31, ring = g>>3
  const int a   = g & 7;
  const int tau = (g < 8) ? (31 - a) : (g < 16) ? (16 + a) : (g < 24) ? (15 - a) : a;
  const int RH  = tau + 1;               // double-rounds (each = 2 kv-tiles of 32)
  const int half = RH * 32;              // stream B kv offset

  const u16* kbase = kb + ((size_t)bb * 2048) * 512 + hkv * 128;
  const u16* vbase = vT + ((size_t)(hkv * 128)) * 4096 + (size_t)bb * 2048;
  const u16* qhb   = qb + ((size_t)bb * 2048) * 2048 + h * 128;

  const int krow_t = tid >> 4, kch = tid & 15;   // K staging coords
  const int vrow_t = tid >> 2, vch = tid & 3;    // V staging coords

  const int qabs = tau * 64 + w * 32 + lq;
  const int qmin = tau * 64 + w * 32;

  bf16x8 qf[8];
  {
    const u16* qp = qhb + (size_t)qabs * 2048;
    #pragma unroll
    for (int c = 0; c < 8; ++c) qf[c] = *(const bf16x8*)(qp + c * 16 + hi * 8);
  }
  f32x16 oacc[4], sA, sB;
  #pragma unroll
  for (int dt = 0; dt < 4; ++dt)
    #pragma unroll
    for (int e = 0; e < 16; ++e) oacc[dt][e] = 0.f;
  float llA = 0.f, llB = 0.f;

  // stage one stream's kv-tile (16 KB: K 8K + V 8K), 128 threads x 8 gld16
  auto STAGE = [&](int st, int jb2) {
    char* bK = lds + st * 16384;
    char* bV = bK + 8192;
    #pragma unroll
    for (int u = 0; u < 4; ++u) {
      const int kr = u * 8 + krow_t;
      gld16(kbase + (size_t)(jb2 + kr) * 512 + ((kch ^ (kr & 15)) << 3),
            bK + u * 2048 + tid * 16);
      // V paired-row layout: slot (R0, C0) holds V[2*R0 + (cp>>2)][8*(cp&3) ..]
      const int R0 = u * 16 + (vrow_t >> 1);          // 0..63
      const int C0 = ((vrow_t & 1) << 2) + vch;       // 0..7
      const int cp = C0 ^ (R0 & 7);
      const int vd = 2 * R0 + (cp >> 2);              // d row 0..127
      gld16(vbase + (size_t)vd * 4096 + jb2 + ((cp & 3) << 3),
            bV + u * 2048 + tid * 16);
    }
  };

  STAGE(0, 0);
  STAGE(1, half);
  __syncthreads();

  for (int r = 0; r < RH; ++r) {
    // ---- QK^T for both streams (independent MFMA chains) ----
    #pragma unroll
    for (int e = 0; e < 16; ++e) { sA[e] = 0.f; sB[e] = 0.f; }
    const char* skA = lds;
    const char* skB = lds + 16384;
    #pragma unroll
    for (int c = 0; c < 8; ++c) {
      const int ch = ((2 * c + hi) ^ (lq & 15)) << 4;
      const bf16x8 kfA = *(const bf16x8*)(skA + lq * 256 + ch);
      const bf16x8 kfB = *(const bf16x8*)(skB + lq * 256 + ch);
      sA = __builtin_amdgcn_mfma_f32_32x32x16_bf16(kfA, qf[c], sA, 0, 0, 0);
      sB = __builtin_amdgcn_mfma_f32_32x32x16_bf16(kfB, qf[c], sB, 0, 0, 0);
    }

    // ---- no-max softmax: p = exp2(s) (|s| <= 16.4 by RMS-norm bound) ----
    const int jbA = r * 32;
    const int jbB = half + r * 32;
    if (jbA + 31 > qmin) {
      #pragma unroll
      for (int e = 0; e < 16; ++e) {
        const int kvl = (e & 3) + ((e >> 2) << 3) + (hi << 2);
        if (jbA + kvl > qabs) sA[e] = -1e30f;
      }
    }
    if (jbB + 31 > qmin) {
      #pragma unroll
      for (int e = 0; e < 16; ++e) {
        const int kvl = (e & 3) + ((e >> 2) << 3) + (hi << 2);
        if (jbB + kvl > qabs) sB[e] = -1e30f;
      }
    }
    float rA = 0.f, rB = 0.f;
    #pragma unroll
    for (int e = 0; e < 16; e += 4) {
      const float a0 = exp2f(sA[e]),     a1 = exp2f(sA[e + 1]);
      const float a2 = exp2f(sA[e + 2]), a3 = exp2f(sA[e + 3]);
      const float b0 = exp2f(sB[e]),     b1 = exp2f(sB[e + 1]);
      const float b2 = exp2f(sB[e + 2]), b3 = exp2f(sB[e + 3]);
      sA[e] = a0; sA[e + 1] = a1; sA[e + 2] = a2; sA[e + 3] = a3;
      sB[e] = b0; sB[e + 1] = b1; sB[e + 2] = b2; sB[e + 3] = b3;
      rA += (a0 + a1) + (a2 + a3);
      rB += (b0 + b1) + (b2 + b3);
    }
    llA += rA; llB += rB;

    // ---- PV for both streams into shared oacc (additive merge) ----
    // Exchange-free: B-fragment = lane's own P values in order (vT pre-permuted).
    const char* svA = lds + 8192;
    const char* svB = lds + 16384 + 8192;
    #pragma unroll
    for (int cc = 0; cc < 2; ++cc) {
      const int c8 = cc * 8;
      u32x4 bwA, bwB;
      bwA.x = cvtpk(sA[c8 + 0], sA[c8 + 1]);
      bwA.y = cvtpk(sA[c8 + 2], sA[c8 + 3]);
      bwA.z = cvtpk(sA[c8 + 4], sA[c8 + 5]);
      bwA.w = cvtpk(sA[c8 + 6], sA[c8 + 7]);
      bwB.x = cvtpk(sB[c8 + 0], sB[c8 + 1]);
      bwB.y = cvtpk(sB[c8 + 2], sB[c8 + 3]);
      bwB.z = cvtpk(sB[c8 + 4], sB[c8 + 5]);
      bwB.w = cvtpk(sB[c8 + 6], sB[c8 + 7]);
      const bf16x8 pfA = __builtin_bit_cast(bf16x8, bwA);
      const bf16x8 pfB = __builtin_bit_cast(bf16x8, bwB);
      #pragma unroll
      for (int dt = 0; dt < 4; ++dt) {
        const int vrow = dt * 16 + (lq >> 1);
        const int cpre = ((lq & 1) << 2) + 2 * cc + hi;
        const int chv = (cpre ^ (vrow & 7)) << 4;
        const bf16x8 vfA = *(const bf16x8*)(svA + vrow * 128 + chv);
        oacc[dt] = __builtin_amdgcn_mfma_f32_32x32x16_bf16(vfA, pfA, oacc[dt], 0, 0, 0);
      }
      #pragma unroll
      for (int dt = 0; dt < 4; ++dt) {
        const int vrow = dt * 16 + (lq >> 1);
        const int cpre = ((lq & 1) << 2) + 2 * cc + hi;
        const int chv = (cpre ^ (vrow & 7)) << 4;
        const bf16x8 vfB = *(const bf16x8*)(svB + vrow * 128 + chv);
        oacc[dt] = __builtin_amdgcn_mfma_f32_32x32x16_bf16(vfB, pfB, oacc[dt], 0, 0, 0);
      }
    }

    // ---- restage (single buffer): wait for readers, stage, wait for data ----
    if (r + 1 < RH) {
      __syncthreads();                 // all waves done reading this round
      STAGE(0, (r + 1) * 32);
      STAGE(1, half + (r + 1) * 32);
      __syncthreads();                 // vmcnt(0) drain + visibility
    }
  }

  // ---- epilogue: merge streams + halves, write O ----
  float ll = llA + llB;
  ll += __shfl_xor(ll, 32);
  const float inv = 1.0f / ll;
  float* ob = out + ((size_t)(bb * 2048 + qabs)) * 2048 + h * 128;
  #pragma unroll
  for (int dt = 0; dt < 4; ++dt)
    #pragma unroll
    for (int qd = 0; qd < 4; ++qd) {
      float4 o4;
      o4.x = oacc[dt][qd * 4 + 0] * inv;
      o4.y = oacc[dt][qd * 4 + 1] * inv;
      o4.z = oacc[dt][qd * 4 + 2] * inv;
      o4.w = oacc[dt][qd * 4 + 3] * inv;
      *(float4*)(ob + dt * 32 + qd * 8 + hi * 4) = o4;
    }
}

extern "C" void kernel_launch(void* const* d_in, const int* in_sizes, int n_in,
                              void* d_out, int out_size, void* d_ws, size_t ws_size,
                              hipStream_t stream) {
  const float* x  = (const float*)d_in[0];
  const float* wq = (const float*)d_in[1];
  const float* wk = (const float*)d_in[2];
  const float* wv = (const float*)d_in[3];
  float* out = (float*)d_out;
  char* ws = (char*)d_ws;

  float* cost = (float*)(ws);                 // 512 KB
  float* sint = (float*)(ws + 524288);        // 512 KB
  u16* xb  = (u16*)(ws + 1048576);            // 16 MB
  u16* wqb = (u16*)(ws + 17825792);           // 8 MB
  u16* wkb = (u16*)(ws + 26214400);           // 2 MB
  u16* wvb = (u16*)(ws + 28311552);           // 2 MB
  u16* qb  = (u16*)(ws + 30408704);           // 16 MB
  u16* kb  = (u16*)(ws + 47185920);           // 4 MB
  u16* vT  = (u16*)(ws + 51380224);           // 4 MB  -> total 55574528
  if (ws_size < 55574528) return;

  k_tables  <<<dim3(512),   dim3(256), 0, stream>>>(cost, sint);
  k_convert <<<dim3(2048),  dim3(256), 0, stream>>>(x, wq, wk, wv, xb, wqb, wkb, wvb);
  k_gemm    <<<dim3(32, 24), dim3(256), 0, stream>>>(xb, wqb, wkb, wvb, qb, kb, vT);
  k_normrope<<<dim3(20480), dim3(256), 0, stream>>>(qb, kb, cost, sint);
  k_attn    <<<dim3(1024),  dim3(128), 0, stream>>>(qb, kb, vT, out);
}

// Round 19
// 160.575 us; speedup vs baseline: 1.1071x; 1.0258x over previous
//
#include <hip/hip_runtime.h>
#include <hip/hip_bf16.h>
#include <cstdint>

typedef __bf16 bf16x8 __attribute__((ext_vector_type(8)));
typedef float f32x4 __attribute__((ext_vector_type(4)));
typedef float f32x16 __attribute__((ext_vector_type(16)));
typedef unsigned int u32;
typedef unsigned short u16;
typedef u32 u32x4 __attribute__((ext_vector_type(4)));

#define AS1 __attribute__((address_space(1)))
#define AS3 __attribute__((address_space(3)))

static __device__ __forceinline__ void gld16(const void* g, void* l) {
  __builtin_amdgcn_global_load_lds((const AS1 u32*)g, (AS3 u32*)l, 16, 0, 0);
}
static __device__ __forceinline__ u16 f2b(float f) {
  return __builtin_bit_cast(u16, __float2bfloat16(f));
}
static __device__ __forceinline__ float b2f(u16 u) {
  return __bfloat162float(__builtin_bit_cast(__hip_bfloat16, u));
}
// one-instruction pack: lo = bf16(a), hi = bf16(b)
static __device__ __forceinline__ u32 cvtpk(float a, float b) {
  u32 r;
  asm("v_cvt_pk_bf16_f32 %0, %1, %2" : "=v"(r) : "v"(a), "v"(b));
  return r;
}

// ---------------- RoPE tables: cos/sin[t][i], t<2048, i<64 ----------------
__global__ void k_tables(float* __restrict__ cost, float* __restrict__ sint) {
  const int idx = blockIdx.x * 256 + threadIdx.x;   // 131072 total
  const int t = idx >> 6, i = idx & 63;
  const float inv = exp2f(-(float)(2 * i) * (13.287712379549449f / 128.0f));
  const float f = (float)t * inv;
  cost[idx] = cosf(f);
  sint[idx] = sinf(f);
}

// ---------------- fp32 -> bf16 convert of x, Wq, Wk, Wv ----------------
__global__ void k_convert(const float* __restrict__ x, const float* __restrict__ wq,
                          const float* __restrict__ wk, const float* __restrict__ wv,
                          u16* __restrict__ xb, u16* __restrict__ wqb,
                          u16* __restrict__ wkb, u16* __restrict__ wvb) {
  for (int i4 = blockIdx.x * blockDim.x + threadIdx.x; i4 < 3670016;
       i4 += gridDim.x * blockDim.x) {
    const int e = i4 * 4;
    const float* s; u16* d;
    if (e < 8388608)        { s = x  + e;              d = xb  + e; }
    else if (e < 12582912)  { int o = e - 8388608;  s = wq + o; d = wqb + o; }
    else if (e < 13631488)  { int o = e - 12582912; s = wk + o; d = wkb + o; }
    else                    { int o = e - 13631488; s = wv + o; d = wvb + o; }
    const float4 v = *(const float4*)s;
    ushort4 o4;
    o4.x = f2b(v.x); o4.y = f2b(v.y); o4.z = f2b(v.z); o4.w = f2b(v.w);
    *(ushort4*)d = o4;
  }
}

// ---------------- fused QKV projection GEMM (bf16 MFMA, m97 structure) ----------------
// BYTE-IDENTICAL to round-11/18 (fusion experiments r16/r17 regressed this kernel).
// vT is written with token-index bits 2<->3 swapped (within each 16-token group):
// makes attention's PV B-fragment equal the lane's OWN softmax values (no shfl).
__global__ __launch_bounds__(256) void k_gemm(
    const u16* __restrict__ xb, const u16* __restrict__ wqb,
    const u16* __restrict__ wkb, const u16* __restrict__ wvb,
    u16* __restrict__ qb, u16* __restrict__ kb, u16* __restrict__ vT) {
  __shared__ __align__(16) char smA[8192];   // [128][32] bf16, source-chunk-swizzled
  __shared__ __align__(16) char smB[8192];
  const int tid = threadIdx.x;
  const int w = tid >> 6, l = tid & 63;
  const int lm = l & 15, g = l >> 4;
  const int m0 = blockIdx.x << 7;
  const int j = blockIdx.y;
  const u16* W; u16* dst; int n0, ldc, vmode;
  if (j < 16)      { W = wqb; dst = qb; n0 = j << 7;        ldc = 2048; vmode = 0; }
  else if (j < 20) { W = wkb; dst = kb; n0 = (j - 16) << 7; ldc = 512;  vmode = 0; }
  else             { W = wvb; dst = vT; n0 = (j - 20) << 7; ldc = 0;    vmode = 1; }

  const int srow = w * 16 + (l >> 2);
  const int scol = l & 3;

  f32x4 acc[4][4];
  #pragma unroll
  for (int a = 0; a < 4; ++a)
    #pragma unroll
    for (int bb = 0; bb < 4; ++bb) { f32x4 zz = {0.f, 0.f, 0.f, 0.f}; acc[a][bb] = zz; }

  const int wm = (w >> 1) << 6, wn = (w & 1) << 6;

  for (int k0 = 0; k0 < 2048; k0 += 32) {
    #pragma unroll
    for (int i = 0; i < 2; ++i) {
      const int r = srow + (i << 6);
      const int sc = (scol ^ (r & 3)) << 3;
      gld16(xb + (m0 + r) * 2048 + k0 + sc, smA + ((i * 4 + w) << 10));
      gld16(W  + (n0 + r) * 2048 + k0 + sc, smB + ((i * 4 + w) << 10));
    }
    __syncthreads();
    bf16x8 af[4], bfr[4];
    #pragma unroll
    for (int mt = 0; mt < 4; ++mt) {
      const int row = wm + mt * 16 + lm;
      af[mt] = *(const bf16x8*)(smA + row * 64 + ((g ^ (row & 3)) << 4));
    }
    #pragma unroll
    for (int nt = 0; nt < 4; ++nt) {
      const int row = wn + nt * 16 + lm;
      bfr[nt] = *(const bf16x8*)(smB + row * 64 + ((g ^ (row & 3)) << 4));
    }
    #pragma unroll
    for (int mt = 0; mt < 4; ++mt)
      #pragma unroll
      for (int nt = 0; nt < 4; ++nt)
        acc[mt][nt] = __builtin_amdgcn_mfma_f32_16x16x32_bf16(af[mt], bfr[nt], acc[mt][nt], 0, 0, 0);
    __syncthreads();
  }

  const int gs = ((g & 1) << 1) | (g >> 1);   // token-index bit2<->bit3 swap for vT
  #pragma unroll
  for (int mt = 0; mt < 4; ++mt) {
    #pragma unroll
    for (int nt = 0; nt < 4; ++nt) {
      const int n = n0 + wn + nt * 16 + lm;
      #pragma unroll
      for (int r = 0; r < 4; ++r) {
        const u16 hv = f2b(acc[mt][nt][r]);
        if (!vmode) {
          const int mq = m0 + wm + mt * 16 + g * 4 + r;
          dst[mq * ldc + n] = hv;
        } else {
          const int mv = m0 + wm + mt * 16 + gs * 4 + r;
          dst[n * 4096 + mv] = hv;
        }
      }
    }
  }
}

// ---------------- RMSNorm + RoPE in-place on K ONLY (16384 items) ----------------
// (q's norm+rope is folded into k_attn's Q-load, in-register.)
__global__ __launch_bounds__(256) void k_normrope(u16* __restrict__ kb,
                                                  const float* __restrict__ cost,
                                                  const float* __restrict__ sint) {
  const int item = blockIdx.x * 4 + (threadIdx.x >> 6);
  const int l = threadIdx.x & 63;
  u16* p = kb + item * 128;
  const int tpos = (item >> 2) & 2047;
  const float f1 = b2f(p[l]);
  const float f2 = b2f(p[l + 64]);
  float ss = f1 * f1 + f2 * f2;
  #pragma unroll
  for (int d = 1; d < 64; d <<= 1) ss += __shfl_xor(ss, d);
  const float rn = rsqrtf(ss * (1.0f / 128.0f) + 1.1920928955078125e-07f);
  const float c = cost[tpos * 64 + l], s = sint[tpos * 64 + l];
  const float x1 = f1 * rn, x2 = f2 * rn;
  p[l]      = f2b(x1 * c + x2 * s);
  p[l + 64] = f2b(x2 * c - x1 * s);
}

// ---------------- causal GQA flash attention: no-max softmax + kv-split, -------------
// ---------------- q-RMSNorm+RoPE folded into Q-load ----------------------------------
// Lane (lq,hi) holds q dims {16c+8hi+j}; RoPE partner d<->d+64 = fragment c<->c+4
// (same lane). ss needs only shfl_xor(32). q scaled by rn*log2(e)/sqrt(128) here,
// so scores stay bounded (|s|<=16.4) and softmax needs no max.
// grid (1024): bid&7 = (b,hkv) XCD-local; ring-complementary tau map; 2-wave
// blocks, 32KB single-buffer LDS -> 4 blocks/CU. kv-split A/B additive streams.
__global__ __launch_bounds__(128) void k_attn(
    const u16* __restrict__ qb, const u16* __restrict__ kb,
    const u16* __restrict__ vT, const float* __restrict__ cost,
    const float* __restrict__ sint, float* __restrict__ out) {
  __shared__ __align__(16) char lds[32768];   // [stream][K 8K | V 8K]
  const int tid = threadIdx.x;
  const int l = tid & 63;
  const int w = tid >> 6;          // wave 0/1 -> q offset 32*w
  const int lq = l & 31;
  const int hi = l >> 5;

  const int bid = blockIdx.x;
  const int cxc = bid & 7;
  const int bb  = cxc >> 2, hkv = cxc & 3;
  const int hsub = (bid >> 3) & 3;
  const int h   = hkv * 4 + hsub;
  const int g   = bid >> 5;              // 0..31, ring = g>>3
  const int a   = g & 7;
  const int tau = (g < 8) ? (31 - a) : (g < 16) ? (16 + a) : (g < 24) ? (15 - a) : a;
  const int RH  = tau + 1;               // double-rounds (each = 2 kv-tiles of 32)
  const int half = RH * 32;              // stream B kv offset

  const u16* kbase = kb + ((size_t)bb * 2048) * 512 + hkv * 128;
  const u16* vbase = vT + ((size_t)(hkv * 128)) * 4096 + (size_t)bb * 2048;
  const u16* qhb   = qb + ((size_t)bb * 2048) * 2048 + h * 128;

  const int krow_t = tid >> 4, kch = tid & 15;   // K staging coords
  const int vrow_t = tid >> 2, vch = tid & 3;    // V staging coords

  const int qabs = tau * 64 + w * 32 + lq;
  const int qmin = tau * 64 + w * 32;

  // ---- Q load + in-register RMSNorm + RoPE (once per block) ----
  bf16x8 qf[8];
  {
    const u16* qp = qhb + (size_t)qabs * 2048;
    bf16x8 qraw[8];
    #pragma unroll
    for (int c = 0; c < 8; ++c) qraw[c] = *(const bf16x8*)(qp + c * 16 + hi * 8);
    float ss = 0.f;
    #pragma unroll
    for (int c = 0; c < 8; ++c)
      #pragma unroll
      for (int jj = 0; jj < 8; ++jj) {
        const float v = (float)qraw[c][jj];
        ss += v * v;
      }
    ss += __shfl_xor(ss, 32);
    const float rn = rsqrtf(ss * (1.0f / 128.0f) + 1.1920928955078125e-07f)
                   * 0.12751742f;   // log2(e)/sqrt(128)
    const float* ct = cost + (size_t)qabs * 64;
    const float* st = sint + (size_t)qabs * 64;
    #pragma unroll
    for (int c = 0; c < 4; ++c) {
      u32 wlo[4], whi[4];
      #pragma unroll
      for (int m = 0; m < 4; ++m) {
        float ylo[2], yhi[2];
        #pragma unroll
        for (int p2 = 0; p2 < 2; ++p2) {
          const int jj = 2 * m + p2;
          const int i = c * 16 + hi * 8 + jj;     // 0..63
          const float cv = ct[i], sv = st[i];
          const float xlo = (float)qraw[c][jj];
          const float xhi = (float)qraw[c + 4][jj];
          ylo[p2] = (xlo * cv + xhi * sv) * rn;
          yhi[p2] = (xhi * cv - xlo * sv) * rn;
        }
        wlo[m] = cvtpk(ylo[0], ylo[1]);
        whi[m] = cvtpk(yhi[0], yhi[1]);
      }
      u32x4 vlo = {wlo[0], wlo[1], wlo[2], wlo[3]};
      u32x4 vhi = {whi[0], whi[1], whi[2], whi[3]};
      qf[c]     = __builtin_bit_cast(bf16x8, vlo);
      qf[c + 4] = __builtin_bit_cast(bf16x8, vhi);
    }
  }

  f32x16 oacc[4], sA, sB;
  #pragma unroll
  for (int dt = 0; dt < 4; ++dt)
    #pragma unroll
    for (int e = 0; e < 16; ++e) oacc[dt][e] = 0.f;
  float llA = 0.f, llB = 0.f;

  // stage one stream's kv-tile (16 KB: K 8K + V 8K), 128 threads x 8 gld16
  auto STAGE = [&](int st, int jb2) {
    char* bK = lds + st * 16384;
    char* bV = bK + 8192;
    #pragma unroll
    for (int u = 0; u < 4; ++u) {
      const int kr = u * 8 + krow_t;
      gld16(kbase + (size_t)(jb2 + kr) * 512 + ((kch ^ (kr & 15)) << 3),
            bK + u * 2048 + tid * 16);
      // V paired-row layout: slot (R0, C0) holds V[2*R0 + (cp>>2)][8*(cp&3) ..]
      const int R0 = u * 16 + (vrow_t >> 1);          // 0..63
      const int C0 = ((vrow_t & 1) << 2) + vch;       // 0..7
      const int cp = C0 ^ (R0 & 7);
      const int vd = 2 * R0 + (cp >> 2);              // d row 0..127
      gld16(vbase + (size_t)vd * 4096 + jb2 + ((cp & 3) << 3),
            bV + u * 2048 + tid * 16);
    }
  };

  STAGE(0, 0);
  STAGE(1, half);
  __syncthreads();

  for (int r = 0; r < RH; ++r) {
    // ---- QK^T for both streams (independent MFMA chains) ----
    #pragma unroll
    for (int e = 0; e < 16; ++e) { sA[e] = 0.f; sB[e] = 0.f; }
    const char* skA = lds;
    const char* skB = lds + 16384;
    #pragma unroll
    for (int c = 0; c < 8; ++c) {
      const int ch = ((2 * c + hi) ^ (lq & 15)) << 4;
      const bf16x8 kfA = *(const bf16x8*)(skA + lq * 256 + ch);
      const bf16x8 kfB = *(const bf16x8*)(skB + lq * 256 + ch);
      sA = __builtin_amdgcn_mfma_f32_32x32x16_bf16(kfA, qf[c], sA, 0, 0, 0);
      sB = __builtin_amdgcn_mfma_f32_32x32x16_bf16(kfB, qf[c], sB, 0, 0, 0);
    }

    // ---- no-max softmax: p = exp2(s) (|s| <= 16.4 by RMS-norm bound) ----
    const int jbA = r * 32;
    const int jbB = half + r * 32;
    if (jbA + 31 > qmin) {
      #pragma unroll
      for (int e = 0; e < 16; ++e) {
        const int kvl = (e & 3) + ((e >> 2) << 3) + (hi << 2);
        if (jbA + kvl > qabs) sA[e] = -1e30f;
      }
    }
    if (jbB + 31 > qmin) {
      #pragma unroll
      for (int e = 0; e < 16; ++e) {
        const int kvl = (e & 3) + ((e >> 2) << 3) + (hi << 2);
        if (jbB + kvl > qabs) sB[e] = -1e30f;
      }
    }
    float rA = 0.f, rB = 0.f;
    #pragma unroll
    for (int e = 0; e < 16; e += 4) {
      const float a0 = exp2f(sA[e]),     a1 = exp2f(sA[e + 1]);
      const float a2 = exp2f(sA[e + 2]), a3 = exp2f(sA[e + 3]);
      const float b0 = exp2f(sB[e]),     b1 = exp2f(sB[e + 1]);
      const float b2 = exp2f(sB[e + 2]), b3 = exp2f(sB[e + 3]);
      sA[e] = a0; sA[e + 1] = a1; sA[e + 2] = a2; sA[e + 3] = a3;
      sB[e] = b0; sB[e + 1] = b1; sB[e + 2] = b2; sB[e + 3] = b3;
      rA += (a0 + a1) + (a2 + a3);
      rB += (b0 + b1) + (b2 + b3);
    }
    llA += rA; llB += rB;

    // ---- PV for both streams into shared oacc (additive merge) ----
    // Exchange-free: B-fragment = lane's own P values in order (vT pre-permuted).
    const char* svA = lds + 8192;
    const char* svB = lds + 16384 + 8192;
    #pragma unroll
    for (int cc = 0; cc < 2; ++cc) {
      const int c8 = cc * 8;
      u32x4 bwA, bwB;
      bwA.x = cvtpk(sA[c8 + 0], sA[c8 + 1]);
      bwA.y = cvtpk(sA[c8 + 2], sA[c8 + 3]);
      bwA.z = cvtpk(sA[c8 + 4], sA[c8 + 5]);
      bwA.w = cvtpk(sA[c8 + 6], sA[c8 + 7]);
      bwB.x = cvtpk(sB[c8 + 0], sB[c8 + 1]);
      bwB.y = cvtpk(sB[c8 + 2], sB[c8 + 3]);
      bwB.z = cvtpk(sB[c8 + 4], sB[c8 + 5]);
      bwB.w = cvtpk(sB[c8 + 6], sB[c8 + 7]);
      const bf16x8 pfA = __builtin_bit_cast(bf16x8, bwA);
      const bf16x8 pfB = __builtin_bit_cast(bf16x8, bwB);
      #pragma unroll
      for (int dt = 0; dt < 4; ++dt) {
        const int vrow = dt * 16 + (lq >> 1);
        const int cpre = ((lq & 1) << 2) + 2 * cc + hi;
        const int chv = (cpre ^ (vrow & 7)) << 4;
        const bf16x8 vfA = *(const bf16x8*)(svA + vrow * 128 + chv);
        oacc[dt] = __builtin_amdgcn_mfma_f32_32x32x16_bf16(vfA, pfA, oacc[dt], 0, 0, 0);
      }
      #pragma unroll
      for (int dt = 0; dt < 4; ++dt) {
        const int vrow = dt * 16 + (lq >> 1);
        const int cpre = ((lq & 1) << 2) + 2 * cc + hi;
        const int chv = (cpre ^ (vrow & 7)) << 4;
        const bf16x8 vfB = *(const bf16x8*)(svB + vrow * 128 + chv);
        oacc[dt] = __builtin_amdgcn_mfma_f32_32x32x16_bf16(vfB, pfB, oacc[dt], 0, 0, 0);
      }
    }

    // ---- restage (single buffer): wait for readers, stage, wait for data ----
    if (r + 1 < RH) {
      __syncthreads();                 // all waves done reading this round
      STAGE(0, (r + 1) * 32);
      STAGE(1, half + (r + 1) * 32);
      __syncthreads();                 // vmcnt(0) drain + visibility
    }
  }

  // ---- epilogue: merge streams + halves, write O ----
  float ll = llA + llB;
  ll += __shfl_xor(ll, 32);
  const float inv = 1.0f / ll;
  float* ob = out + ((size_t)(bb * 2048 + qabs)) * 2048 + h * 128;
  #pragma unroll
  for (int dt = 0; dt < 4; ++dt)
    #pragma unroll
    for (int qd = 0; qd < 4; ++qd) {
      float4 o4;
      o4.x = oacc[dt][qd * 4 + 0] * inv;
      o4.y = oacc[dt][qd * 4 + 1] * inv;
      o4.z = oacc[dt][qd * 4 + 2] * inv;
      o4.w = oacc[dt][qd * 4 + 3] * inv;
      *(float4*)(ob + dt * 32 + qd * 8 + hi * 4) = o4;
    }
}

extern "C" void kernel_launch(void* const* d_in, const int* in_sizes, int n_in,
                              void* d_out, int out_size, void* d_ws, size_t ws_size,
                              hipStream_t stream) {
  const float* x  = (const float*)d_in[0];
  const float* wq = (const float*)d_in[1];
  const float* wk = (const float*)d_in[2];
  const float* wv = (const float*)d_in[3];
  float* out = (float*)d_out;
  char* ws = (char*)d_ws;

  float* cost = (float*)(ws);                 // 512 KB
  float* sint = (float*)(ws + 524288);        // 512 KB
  u16* xb  = (u16*)(ws + 1048576);            // 16 MB
  u16* wqb = (u16*)(ws + 17825792);           // 8 MB
  u16* wkb = (u16*)(ws + 26214400);           // 2 MB
  u16* wvb = (u16*)(ws + 28311552);           // 2 MB
  u16* qb  = (u16*)(ws + 30408704);           // 16 MB
  u16* kb  = (u16*)(ws + 47185920);           // 4 MB
  u16* vT  = (u16*)(ws + 51380224);           // 4 MB  -> total 55574528
  if (ws_size < 55574528) return;

  k_tables  <<<dim3(512),   dim3(256), 0, stream>>>(cost, sint);
  k_convert <<<dim3(2048),  dim3(256), 0, stream>>>(x, wq, wk, wv, xb, wqb, wkb, wvb);
  k_gemm    <<<dim3(32, 24), dim3(256), 0, stream>>>(xb, wqb, wkb, wvb, qb, kb, vT);
  k_normrope<<<dim3(4096),  dim3(256), 0, stream>>>(kb, cost, sint);
  k_attn    <<<dim3(1024),  dim3(128), 0, stream>>>(qb, kb, vT, cost, sint, out);
}

// Round 20
// 157.251 us; speedup vs baseline: 1.1305x; 1.0211x over previous
//
#include <hip/hip_runtime.h>
#include <hip/hip_bf16.h>
#include <cstdint>

typedef __bf16 bf16x8 __attribute__((ext_vector_type(8)));
typedef float f32x4 __attribute__((ext_vector_type(4)));
typedef float f32x16 __attribute__((ext_vector_type(16)));
typedef unsigned int u32;
typedef unsigned short u16;
typedef u32 u32x4 __attribute__((ext_vector_type(4)));

#define AS1 __attribute__((address_space(1)))
#define AS3 __attribute__((address_space(3)))

static __device__ __forceinline__ void gld16(const void* g, void* l) {
  __builtin_amdgcn_global_load_lds((const AS1 u32*)g, (AS3 u32*)l, 16, 0, 0);
}
static __device__ __forceinline__ u16 f2b(float f) {
  return __builtin_bit_cast(u16, __float2bfloat16(f));
}
static __device__ __forceinline__ float b2f(u16 u) {
  return __bfloat162float(__builtin_bit_cast(__hip_bfloat16, u));
}
// one-instruction pack: lo = bf16(a), hi = bf16(b)
static __device__ __forceinline__ u32 cvtpk(float a, float b) {
  u32 r;
  asm("v_cvt_pk_bf16_f32 %0, %1, %2" : "=v"(r) : "v"(a), "v"(b));
  return r;
}

// ---------------- prep: RoPE tables (packed float2) + fp32->bf16 convert ----------------
// blocks 0..511: cst[t][i] = {cos,sin} (131072 items). blocks 512+: convert (3670016 f4).
__global__ __launch_bounds__(256) void k_prep(
    const float* __restrict__ x, const float* __restrict__ wq,
    const float* __restrict__ wk, const float* __restrict__ wv,
    u16* __restrict__ xb, u16* __restrict__ wqb,
    u16* __restrict__ wkb, u16* __restrict__ wvb,
    float2* __restrict__ cst) {
  const int idx = blockIdx.x * 256 + threadIdx.x;
  if (idx < 131072) {
    const int t = idx >> 6, i = idx & 63;
    const float inv = exp2f(-(float)(2 * i) * (13.287712379549449f / 128.0f));
    const float f = (float)t * inv;
    cst[idx] = make_float2(cosf(f), sinf(f));
    return;
  }
  const int i4 = idx - 131072;              // 0 .. 3670015
  const int e = i4 * 4;
  const float* s; u16* d;
  if (e < 8388608)        { s = x  + e;              d = xb  + e; }
  else if (e < 12582912)  { int o = e - 8388608;  s = wq + o; d = wqb + o; }
  else if (e < 13631488)  { int o = e - 12582912; s = wk + o; d = wkb + o; }
  else                    { int o = e - 13631488; s = wv + o; d = wvb + o; }
  const float4 v = *(const float4*)s;
  ushort4 o4;
  o4.x = f2b(v.x); o4.y = f2b(v.y); o4.z = f2b(v.z); o4.w = f2b(v.w);
  *(ushort4*)d = o4;
}

// ---------------- fused QKV projection GEMM (bf16 MFMA, m97 structure) ----------------
// BYTE-IDENTICAL K-loop to round-11/18 (fusion experiments r16/r17 regressed this).
// vT is written with token-index bits 2<->3 swapped (within each 16-token group):
// makes attention's PV B-fragment equal the lane's OWN softmax values (no shfl).
__global__ __launch_bounds__(256) void k_gemm(
    const u16* __restrict__ xb, const u16* __restrict__ wqb,
    const u16* __restrict__ wkb, const u16* __restrict__ wvb,
    u16* __restrict__ qb, u16* __restrict__ kb, u16* __restrict__ vT) {
  __shared__ __align__(16) char smA[8192];   // [128][32] bf16, source-chunk-swizzled
  __shared__ __align__(16) char smB[8192];
  const int tid = threadIdx.x;
  const int w = tid >> 6, l = tid & 63;
  const int lm = l & 15, g = l >> 4;
  const int m0 = blockIdx.x << 7;
  const int j = blockIdx.y;
  const u16* W; u16* dst; int n0, ldc, vmode;
  if (j < 16)      { W = wqb; dst = qb; n0 = j << 7;        ldc = 2048; vmode = 0; }
  else if (j < 20) { W = wkb; dst = kb; n0 = (j - 16) << 7; ldc = 512;  vmode = 0; }
  else             { W = wvb; dst = vT; n0 = (j - 20) << 7; ldc = 0;    vmode = 1; }

  const int srow = w * 16 + (l >> 2);
  const int scol = l & 3;

  f32x4 acc[4][4];
  #pragma unroll
  for (int a = 0; a < 4; ++a)
    #pragma unroll
    for (int bb = 0; bb < 4; ++bb) { f32x4 zz = {0.f, 0.f, 0.f, 0.f}; acc[a][bb] = zz; }

  const int wm = (w >> 1) << 6, wn = (w & 1) << 6;

  for (int k0 = 0; k0 < 2048; k0 += 32) {
    #pragma unroll
    for (int i = 0; i < 2; ++i) {
      const int r = srow + (i << 6);
      const int sc = (scol ^ (r & 3)) << 3;
      gld16(xb + (m0 + r) * 2048 + k0 + sc, smA + ((i * 4 + w) << 10));
      gld16(W  + (n0 + r) * 2048 + k0 + sc, smB + ((i * 4 + w) << 10));
    }
    __syncthreads();
    bf16x8 af[4], bfr[4];
    #pragma unroll
    for (int mt = 0; mt < 4; ++mt) {
      const int row = wm + mt * 16 + lm;
      af[mt] = *(const bf16x8*)(smA + row * 64 + ((g ^ (row & 3)) << 4));
    }
    #pragma unroll
    for (int nt = 0; nt < 4; ++nt) {
      const int row = wn + nt * 16 + lm;
      bfr[nt] = *(const bf16x8*)(smB + row * 64 + ((g ^ (row & 3)) << 4));
    }
    #pragma unroll
    for (int mt = 0; mt < 4; ++mt)
      #pragma unroll
      for (int nt = 0; nt < 4; ++nt)
        acc[mt][nt] = __builtin_amdgcn_mfma_f32_16x16x32_bf16(af[mt], bfr[nt], acc[mt][nt], 0, 0, 0);
    __syncthreads();
  }

  const int gs = ((g & 1) << 1) | (g >> 1);   // token-index bit2<->bit3 swap for vT
  #pragma unroll
  for (int mt = 0; mt < 4; ++mt) {
    #pragma unroll
    for (int nt = 0; nt < 4; ++nt) {
      const int n = n0 + wn + nt * 16 + lm;
      #pragma unroll
      for (int r = 0; r < 4; ++r) {
        const u16 hv = f2b(acc[mt][nt][r]);
        if (!vmode) {
          const int mq = m0 + wm + mt * 16 + g * 4 + r;
          dst[mq * ldc + n] = hv;
        } else {
          const int mv = m0 + wm + mt * 16 + gs * 4 + r;
          dst[n * 4096 + mv] = hv;
        }
      }
    }
  }
}

// ---------------- RMSNorm + RoPE in-place on K ONLY (16384 items) ----------------
// (q's norm+rope is folded into k_attn's Q-load, in-register.)
__global__ __launch_bounds__(256) void k_normrope(u16* __restrict__ kb,
                                                  const float2* __restrict__ cst) {
  const int item = blockIdx.x * 4 + (threadIdx.x >> 6);
  const int l = threadIdx.x & 63;
  u16* p = kb + item * 128;
  const int tpos = (item >> 2) & 2047;
  const float f1 = b2f(p[l]);
  const float f2 = b2f(p[l + 64]);
  float ss = f1 * f1 + f2 * f2;
  #pragma unroll
  for (int d = 1; d < 64; d <<= 1) ss += __shfl_xor(ss, d);
  const float rn = rsqrtf(ss * (1.0f / 128.0f) + 1.1920928955078125e-07f);
  const float2 cs = cst[tpos * 64 + l];
  const float x1 = f1 * rn, x2 = f2 * rn;
  p[l]      = f2b(x1 * cs.x + x2 * cs.y);
  p[l + 64] = f2b(x2 * cs.x - x1 * cs.y);
}

// ---------------- causal GQA flash attention: no-max softmax + kv-split, -------------
// ---------------- q-RMSNorm+RoPE folded into Q-load (packed float2 tables) -----------
// Lane (lq,hi) holds q dims {16c+8hi+j}; RoPE partner d<->d+64 = fragment c<->c+4
// (same lane). ss needs only shfl_xor(32). q scaled by rn*log2(e)/sqrt(128) here,
// so scores stay bounded (|s|<=16.4) and softmax needs no max.
// grid (1024): bid&7 = (b,hkv) XCD-local; ring-complementary tau map; 2-wave
// blocks, 32KB single-buffer LDS -> 4 blocks/CU. kv-split A/B additive streams.
__global__ __launch_bounds__(128) void k_attn(
    const u16* __restrict__ qb, const u16* __restrict__ kb,
    const u16* __restrict__ vT, const float2* __restrict__ cst,
    float* __restrict__ out) {
  __shared__ __align__(16) char lds[32768];   // [stream][K 8K | V 8K]
  const int tid = threadIdx.x;
  const int l = tid & 63;
  const int w = tid >> 6;          // wave 0/1 -> q offset 32*w
  const int lq = l & 31;
  const int hi = l >> 5;

  const int bid = blockIdx.x;
  const int cxc = bid & 7;
  const int bb  = cxc >> 2, hkv = cxc & 3;
  const int hsub = (bid >> 3) & 3;
  const int h   = hkv * 4 + hsub;
  const int g   = bid >> 5;              // 0..31, ring = g>>3
  const int a   = g & 7;
  const int tau = (g < 8) ? (31 - a) : (g < 16) ? (16 + a) : (g < 24) ? (15 - a) : a;
  const int RH  = tau + 1;               // double-rounds (each = 2 kv-tiles of 32)
  const int half = RH * 32;              // stream B kv offset

  const u16* kbase = kb + ((size_t)bb * 2048) * 512 + hkv * 128;
  const u16* vbase = vT + ((size_t)(hkv * 128)) * 4096 + (size_t)bb * 2048;
  const u16* qhb   = qb + ((size_t)bb * 2048) * 2048 + h * 128;

  const int krow_t = tid >> 4, kch = tid & 15;   // K staging coords
  const int vrow_t = tid >> 2, vch = tid & 3;    // V staging coords

  const int qabs = tau * 64 + w * 32 + lq;
  const int qmin = tau * 64 + w * 32;

  // ---- Q load + in-register RMSNorm + RoPE (once per block) ----
  bf16x8 qf[8];
  {
    const u16* qp = qhb + (size_t)qabs * 2048;
    bf16x8 qraw[8];
    #pragma unroll
    for (int c = 0; c < 8; ++c) qraw[c] = *(const bf16x8*)(qp + c * 16 + hi * 8);
    float ss = 0.f;
    #pragma unroll
    for (int c = 0; c < 8; ++c)
      #pragma unroll
      for (int jj = 0; jj < 8; ++jj) {
        const float v = (float)qraw[c][jj];
        ss += v * v;
      }
    ss += __shfl_xor(ss, 32);
    const float rn = rsqrtf(ss * (1.0f / 128.0f) + 1.1920928955078125e-07f)
                   * 0.12751742f;   // log2(e)/sqrt(128)
    const float2* cs2 = cst + (size_t)qabs * 64;
    #pragma unroll
    for (int c = 0; c < 4; ++c) {
      u32 wlo[4], whi[4];
      #pragma unroll
      for (int m = 0; m < 4; ++m) {
        float ylo[2], yhi[2];
        #pragma unroll
        for (int p2 = 0; p2 < 2; ++p2) {
          const int jj = 2 * m + p2;
          const int i = c * 16 + hi * 8 + jj;     // 0..63
          const float2 cs = cs2[i];
          const float xlo = (float)qraw[c][jj];
          const float xhi = (float)qraw[c + 4][jj];
          ylo[p2] = (xlo * cs.x + xhi * cs.y) * rn;
          yhi[p2] = (xhi * cs.x - xlo * cs.y) * rn;
        }
        wlo[m] = cvtpk(ylo[0], ylo[1]);
        whi[m] = cvtpk(yhi[0], yhi[1]);
      }
      u32x4 vlo = {wlo[0], wlo[1], wlo[2], wlo[3]};
      u32x4 vhi = {whi[0], whi[1], whi[2], whi[3]};
      qf[c]     = __builtin_bit_cast(bf16x8, vlo);
      qf[c + 4] = __builtin_bit_cast(bf16x8, vhi);
    }
  }

  f32x16 oacc[4], sA, sB;
  #pragma unroll
  for (int dt = 0; dt < 4; ++dt)
    #pragma unroll
    for (int e = 0; e < 16; ++e) oacc[dt][e] = 0.f;
  float llA = 0.f, llB = 0.f;

  // stage one stream's kv-tile (16 KB: K 8K + V 8K), 128 threads x 8 gld16
  auto STAGE = [&](int st, int jb2) {
    char* bK = lds + st * 16384;
    char* bV = bK + 8192;
    #pragma unroll
    for (int u = 0; u < 4; ++u) {
      const int kr = u * 8 + krow_t;
      gld16(kbase + (size_t)(jb2 + kr) * 512 + ((kch ^ (kr & 15)) << 3),
            bK + u * 2048 + tid * 16);
      // V paired-row layout: slot (R0, C0) holds V[2*R0 + (cp>>2)][8*(cp&3) ..]
      const int R0 = u * 16 + (vrow_t >> 1);          // 0..63
      const int C0 = ((vrow_t & 1) << 2) + vch;       // 0..7
      const int cp = C0 ^ (R0 & 7);
      const int vd = 2 * R0 + (cp >> 2);              // d row 0..127
      gld16(vbase + (size_t)vd * 4096 + jb2 + ((cp & 3) << 3),
            bV + u * 2048 + tid * 16);
    }
  };

  STAGE(0, 0);
  STAGE(1, half);
  __syncthreads();

  for (int r = 0; r < RH; ++r) {
    // ---- QK^T for both streams (independent MFMA chains) ----
    #pragma unroll
    for (int e = 0; e < 16; ++e) { sA[e] = 0.f; sB[e] = 0.f; }
    const char* skA = lds;
    const char* skB = lds + 16384;
    #pragma unroll
    for (int c = 0; c < 8; ++c) {
      const int ch = ((2 * c + hi) ^ (lq & 15)) << 4;
      const bf16x8 kfA = *(const bf16x8*)(skA + lq * 256 + ch);
      const bf16x8 kfB = *(const bf16x8*)(skB + lq * 256 + ch);
      sA = __builtin_amdgcn_mfma_f32_32x32x16_bf16(kfA, qf[c], sA, 0, 0, 0);
      sB = __builtin_amdgcn_mfma_f32_32x32x16_bf16(kfB, qf[c], sB, 0, 0, 0);
    }

    // ---- no-max softmax: p = exp2(s) (|s| <= 16.4 by RMS-norm bound) ----
    const int jbA = r * 32;
    const int jbB = half + r * 32;
    if (jbA + 31 > qmin) {
      #pragma unroll
      for (int e = 0; e < 16; ++e) {
        const int kvl = (e & 3) + ((e >> 2) << 3) + (hi << 2);
        if (jbA + kvl > qabs) sA[e] = -1e30f;
      }
    }
    if (jbB + 31 > qmin) {
      #pragma unroll
      for (int e = 0; e < 16; ++e) {
        const int kvl = (e & 3) + ((e >> 2) << 3) + (hi << 2);
        if (jbB + kvl > qabs) sB[e] = -1e30f;
      }
    }
    float rA = 0.f, rB = 0.f;
    #pragma unroll
    for (int e = 0; e < 16; e += 4) {
      const float a0 = exp2f(sA[e]),     a1 = exp2f(sA[e + 1]);
      const float a2 = exp2f(sA[e + 2]), a3 = exp2f(sA[e + 3]);
      const float b0 = exp2f(sB[e]),     b1 = exp2f(sB[e + 1]);
      const float b2 = exp2f(sB[e + 2]), b3 = exp2f(sB[e + 3]);
      sA[e] = a0; sA[e + 1] = a1; sA[e + 2] = a2; sA[e + 3] = a3;
      sB[e] = b0; sB[e + 1] = b1; sB[e + 2] = b2; sB[e + 3] = b3;
      rA += (a0 + a1) + (a2 + a3);
      rB += (b0 + b1) + (b2 + b3);
    }
    llA += rA; llB += rB;

    // ---- PV for both streams into shared oacc (additive merge) ----
    // Exchange-free: B-fragment = lane's own P values in order (vT pre-permuted).
    const char* svA = lds + 8192;
    const char* svB = lds + 16384 + 8192;
    #pragma unroll
    for (int cc = 0; cc < 2; ++cc) {
      const int c8 = cc * 8;
      u32x4 bwA, bwB;
      bwA.x = cvtpk(sA[c8 + 0], sA[c8 + 1]);
      bwA.y = cvtpk(sA[c8 + 2], sA[c8 + 3]);
      bwA.z = cvtpk(sA[c8 + 4], sA[c8 + 5]);
      bwA.w = cvtpk(sA[c8 + 6], sA[c8 + 7]);
      bwB.x = cvtpk(sB[c8 + 0], sB[c8 + 1]);
      bwB.y = cvtpk(sB[c8 + 2], sB[c8 + 3]);
      bwB.z = cvtpk(sB[c8 + 4], sB[c8 + 5]);
      bwB.w = cvtpk(sB[c8 + 6], sB[c8 + 7]);
      const bf16x8 pfA = __builtin_bit_cast(bf16x8, bwA);
      const bf16x8 pfB = __builtin_bit_cast(bf16x8, bwB);
      #pragma unroll
      for (int dt = 0; dt < 4; ++dt) {
        const int vrow = dt * 16 + (lq >> 1);
        const int cpre = ((lq & 1) << 2) + 2 * cc + hi;
        const int chv = (cpre ^ (vrow & 7)) << 4;
        const bf16x8 vfA = *(const bf16x8*)(svA + vrow * 128 + chv);
        oacc[dt] = __builtin_amdgcn_mfma_f32_32x32x16_bf16(vfA, pfA, oacc[dt], 0, 0, 0);
      }
      #pragma unroll
      for (int dt = 0; dt < 4; ++dt) {
        const int vrow = dt * 16 + (lq >> 1);
        const int cpre = ((lq & 1) << 2) + 2 * cc + hi;
        const int chv = (cpre ^ (vrow & 7)) << 4;
        const bf16x8 vfB = *(const bf16x8*)(svB + vrow * 128 + chv);
        oacc[dt] = __builtin_amdgcn_mfma_f32_32x32x16_bf16(vfB, pfB, oacc[dt], 0, 0, 0);
      }
    }

    // ---- restage (single buffer): wait for readers, stage, wait for data ----
    if (r + 1 < RH) {
      __syncthreads();                 // all waves done reading this round
      STAGE(0, (r + 1) * 32);
      STAGE(1, half + (r + 1) * 32);
      __syncthreads();                 // vmcnt(0) drain + visibility
    }
  }

  // ---- epilogue: merge streams + halves, write O ----
  float ll = llA + llB;
  ll += __shfl_xor(ll, 32);
  const float inv = 1.0f / ll;
  float* ob = out + ((size_t)(bb * 2048 + qabs)) * 2048 + h * 128;
  #pragma unroll
  for (int dt = 0; dt < 4; ++dt)
    #pragma unroll
    for (int qd = 0; qd < 4; ++qd) {
      float4 o4;
      o4.x = oacc[dt][qd * 4 + 0] * inv;
      o4.y = oacc[dt][qd * 4 + 1] * inv;
      o4.z = oacc[dt][qd * 4 + 2] * inv;
      o4.w = oacc[dt][qd * 4 + 3] * inv;
      *(float4*)(ob + dt * 32 + qd * 8 + hi * 4) = o4;
    }
}

extern "C" void kernel_launch(void* const* d_in, const int* in_sizes, int n_in,
                              void* d_out, int out_size, void* d_ws, size_t ws_size,
                              hipStream_t stream) {
  const float* x  = (const float*)d_in[0];
  const float* wq = (const float*)d_in[1];
  const float* wk = (const float*)d_in[2];
  const float* wv = (const float*)d_in[3];
  float* out = (float*)d_out;
  char* ws = (char*)d_ws;

  float2* cst = (float2*)(ws);                // 1 MB packed {cos,sin}
  u16* xb  = (u16*)(ws + 1048576);            // 16 MB
  u16* wqb = (u16*)(ws + 17825792);           // 8 MB
  u16* wkb = (u16*)(ws + 26214400);           // 2 MB
  u16* wvb = (u16*)(ws + 28311552);           // 2 MB
  u16* qb  = (u16*)(ws + 30408704);           // 16 MB
  u16* kb  = (u16*)(ws + 47185920);           // 4 MB
  u16* vT  = (u16*)(ws + 51380224);           // 4 MB  -> total 55574528
  if (ws_size < 55574528) return;

  k_prep    <<<dim3(14848), dim3(256), 0, stream>>>(x, wq, wk, wv, xb, wqb, wkb, wvb, cst);
  k_gemm    <<<dim3(32, 24), dim3(256), 0, stream>>>(xb, wqb, wkb, wvb, qb, kb, vT);
  k_normrope<<<dim3(4096),  dim3(256), 0, stream>>>(kb, cst);
  k_attn    <<<dim3(1024),  dim3(128), 0, stream>>>(qb, kb, vT, cst, out);
}